// Round 7
// baseline (654.499 us; speedup 1.0000x reference)
//
#include <hip/hip_runtime.h>
#include <cmath>

typedef __attribute__((ext_vector_type(8))) short bf16x8;
typedef __attribute__((ext_vector_type(4))) float f32x4;
typedef unsigned short u16;

#define ATTN_SCALE 0.25f

__device__ inline u16 f2bf(float x) {
    union { float f; unsigned u; } v; v.f = x;
    unsigned r = v.u + 0x7FFFu + ((v.u >> 16) & 1u);
    return (u16)(r >> 16);
}
__device__ inline float bf2f(u16 u) {
    union { unsigned u; float f; } v; v.u = ((unsigned)u) << 16; return v.f;
}
__device__ inline float fast_tanh(float x) {
    float xc = fminf(fmaxf(x, -15.f), 15.f);
    float t = __expf(2.f * xc);
    return (t - 1.f) * __builtin_amdgcn_rcpf(t + 1.f);
}

// ---------- CSR build ----------

__global__ __launch_bounds__(256) void hist_kernel(const int* __restrict__ dst,
                                                   int* __restrict__ counts, int E) {
    int i = blockIdx.x * 256 + threadIdx.x;
    if (i < E) atomicAdd(&counts[dst[i]], 1);
}

__global__ __launch_bounds__(256) void scan1(const int* __restrict__ counts,
                                             int* __restrict__ tmp, int* __restrict__ bsum, int N) {
    __shared__ int wsum[4];
    int b = blockIdx.x, t = threadIdx.x;
    int base = b * 1024 + t * 4;
    int v0 = (base + 0 < N) ? counts[base + 0] : 0;
    int v1 = (base + 1 < N) ? counts[base + 1] : 0;
    int v2 = (base + 2 < N) ? counts[base + 2] : 0;
    int v3 = (base + 3 < N) ? counts[base + 3] : 0;
    int p0 = v0, p1 = p0 + v1, p2 = p1 + v2, p3 = p2 + v3;
    int s = p3;
    int lane = t & 63, wid = t >> 6;
    int sc = s;
    #pragma unroll
    for (int d = 1; d < 64; d <<= 1) {
        int o = __shfl_up(sc, d);
        if (lane >= d) sc += o;
    }
    if (lane == 63) wsum[wid] = sc;
    __syncthreads();
    int wof = 0;
    #pragma unroll
    for (int i = 0; i < 4; ++i) if (i < wid) wof += wsum[i];
    int excl = wof + sc - s;
    if (base + 0 < N) tmp[base + 0] = excl + p0;
    if (base + 1 < N) tmp[base + 1] = excl + p1;
    if (base + 2 < N) tmp[base + 2] = excl + p2;
    if (base + 3 < N) tmp[base + 3] = excl + p3;
    if (t == 255) bsum[b] = wof + sc;
}

__global__ void scan2(int* __restrict__ bsum, int nb) {
    int t = threadIdx.x;
    int v = (t < nb) ? bsum[t] : 0;
    int sc = v;
    #pragma unroll
    for (int d = 1; d < 64; d <<= 1) {
        int o = __shfl_up(sc, d);
        if (t >= d) sc += o;
    }
    if (t < nb) bsum[t] = sc - v;
}

__global__ __launch_bounds__(256) void scan3(const int* __restrict__ tmp,
                                             const int* __restrict__ bsum,
                                             int* __restrict__ offsets, int N) {
    int i = blockIdx.x * 256 + threadIdx.x;
    if (i < N) offsets[i + 1] = tmp[i] + bsum[i >> 10];
    if (i == 0) offsets[0] = 0;
}

__global__ __launch_bounds__(256) void copy_kernel(const int* __restrict__ a,
                                                   int* __restrict__ b, int n) {
    int i = blockIdx.x * 256 + threadIdx.x;
    if (i < n) b[i] = a[i];
}

__global__ __launch_bounds__(256) void scatter_kernel(const int* __restrict__ dst,
                                                      int* __restrict__ cursor,
                                                      int* __restrict__ eidx, int E) {
    int i = blockIdx.x * 256 + threadIdx.x;
    if (i < E) {
        int p = atomicAdd(&cursor[dst[i]], 1);
        eidx[p] = i;
    }
}

// ---------- weight -> MFMA B-fragment (bf16, frag-linear) ----------
__global__ __launch_bounds__(256) void make_frag(const float* __restrict__ W,
                                                 short* __restrict__ out) {
    int id = blockIdx.x * 256 + threadIdx.x;
    if (id >= 2048) return;
    int l = id & 63, t16 = id >> 6;
    int kk = t16 & 3, n = t16 >> 2;
    int col = n * 16 + (l & 15);
    int k0 = kk * 32 + (l >> 4) * 8;
    #pragma unroll
    for (int j = 0; j < 8; ++j)
        out[id * 8 + j] = (short)f2bf(W[col * 128 + k0 + j]);
}

// ---------- qkv GEMM: 3 channels, bf16 outputs ----------

__global__ __launch_bounds__(256) void qkv_gemm(
    const float* __restrict__ X, const short* __restrict__ frag,
    const float* __restrict__ bias,
    u16* __restrict__ Y0, u16* __restrict__ Y1, u16* __restrict__ Y2, int R)
{
    __shared__ __align__(16) char lds[64 * 256];
    const int t = threadIdx.x;
    const int base = blockIdx.x * 64;
    for (int i = 0; i < 8; ++i) {
        int flat = i * 1024 + t * 4;
        int r = flat >> 7, k = flat & 127;
        float4 v = make_float4(0.f, 0.f, 0.f, 0.f);
        if (base + r < R) v = *reinterpret_cast<const float4*>(&X[(size_t)(base + r) * 128 + k]);
        ushort4 b;
        b.x = f2bf(v.x); b.y = f2bf(v.y); b.z = f2bf(v.z); b.w = f2bf(v.w);
        *reinterpret_cast<ushort4*>(lds + r * 256 + ((k * 2) ^ ((r & 15) << 4))) = b;
    }
    __syncthreads();
    const int w = t >> 6, l = t & 63, lr = l & 15, lg = l >> 4;
    const int rowbase = (w * 16 + lr) * 256, swz = lr << 4;
    bf16x8 afr[4];
    #pragma unroll
    for (int kk = 0; kk < 4; ++kk)
        afr[kk] = *reinterpret_cast<const bf16x8*>(lds + rowbase + ((kk * 64 + lg * 16) ^ swz));
    for (int ch = 0; ch < 3; ++ch) {
        const bf16x8* bf = reinterpret_cast<const bf16x8*>(frag + ch * 2048 * 8);
        f32x4 acc[8];
        #pragma unroll
        for (int n = 0; n < 8; ++n) acc[n] = (f32x4){0.f, 0.f, 0.f, 0.f};
        #pragma unroll
        for (int n = 0; n < 8; ++n)
            #pragma unroll
            for (int kk = 0; kk < 4; ++kk)
                acc[n] = __builtin_amdgcn_mfma_f32_16x16x32_bf16(afr[kk], bf[(n * 4 + kk) * 64 + l],
                                                                 acc[n], 0, 0, 0);
        u16* Y = (ch == 0) ? Y0 : (ch == 1) ? Y1 : Y2;
        #pragma unroll
        for (int n = 0; n < 8; ++n) {
            int col = n * 16 + lr;
            float bv = bias[ch * 128 + col];
            #pragma unroll
            for (int reg = 0; reg < 4; ++reg) {
                int r = base + w * 16 + lg * 4 + reg;
                if (r < R) Y[(size_t)r * 128 + col] = f2bf(acc[n][reg] + bv);
            }
        }
    }
}

// ---------- generic rows x 128 @ 128x128 MFMA GEMM, f32 out (hproj) ----------

__global__ __launch_bounds__(256) void gemm128(
    const float* __restrict__ X, const short* __restrict__ frag,
    const float* __restrict__ bias, float* __restrict__ Y, int R)
{
    __shared__ __align__(16) char lds[64 * 256];
    const int t = threadIdx.x;
    const int base = blockIdx.x * 64;
    for (int i = 0; i < 8; ++i) {
        int flat = i * 1024 + t * 4;
        int r = flat >> 7, k = flat & 127;
        float4 v = make_float4(0.f, 0.f, 0.f, 0.f);
        if (base + r < R) v = *reinterpret_cast<const float4*>(&X[(size_t)(base + r) * 128 + k]);
        ushort4 b;
        b.x = f2bf(v.x); b.y = f2bf(v.y); b.z = f2bf(v.z); b.w = f2bf(v.w);
        *reinterpret_cast<ushort4*>(lds + r * 256 + ((k * 2) ^ ((r & 15) << 4))) = b;
    }
    __syncthreads();
    const int w = t >> 6, l = t & 63, lr = l & 15, lg = l >> 4;
    const int rowbase = (w * 16 + lr) * 256, swz = lr << 4;
    bf16x8 afr[4];
    #pragma unroll
    for (int kk = 0; kk < 4; ++kk)
        afr[kk] = *reinterpret_cast<const bf16x8*>(lds + rowbase + ((kk * 64 + lg * 16) ^ swz));
    const bf16x8* bf = reinterpret_cast<const bf16x8*>(frag);
    f32x4 acc[8];
    #pragma unroll
    for (int n = 0; n < 8; ++n) acc[n] = (f32x4){0.f, 0.f, 0.f, 0.f};
    #pragma unroll
    for (int n = 0; n < 8; ++n)
        #pragma unroll
        for (int kk = 0; kk < 4; ++kk)
            acc[n] = __builtin_amdgcn_mfma_f32_16x16x32_bf16(afr[kk], bf[(n * 4 + kk) * 64 + l],
                                                             acc[n], 0, 0, 0);
    #pragma unroll
    for (int n = 0; n < 8; ++n) {
        int col = n * 16 + lr;
        float bv = bias[n * 16 + lr];
        #pragma unroll
        for (int reg = 0; reg < 4; ++reg) {
            int r = base + w * 16 + lg * 4 + reg;
            if (r < R) Y[(size_t)r * 128 + col] = acc[n][reg] + bv;
        }
    }
}

// ---------- fused edge kernel: persistent grid-stride, 2-deep LDS pipeline ----------
// Per tile: {barrier; GEMM1(buf[cur]); B-gathers; epilogue->score(buf[cur]);
// logit; issue staging loads T+stride; GEMM2->e_out; ds_write buf[cur^1];
// A-gathers T+stride}. One barrier per tile; staging/gather latency hides
// under compute of the current tile. No waves/EU clamp (R5 spill lesson).

__global__ __launch_bounds__(256) void edge_mfma(
    const float* __restrict__ e, const int* __restrict__ src, const int* __restrict__ dst,
    const short* __restrict__ cfrag, const float* __restrict__ cbias,
    const short* __restrict__ efrag, const float* __restrict__ ebias,
    const u16* __restrict__ qbh, const u16* __restrict__ kbh,
    float* __restrict__ e_out, float* __restrict__ mean_out,
    float* __restrict__ logit, int E, int ntiles)
{
    __shared__ __align__(16) char lds[2][64 * 256];
    const int t = threadIdx.x;
    const int w = t >> 6, l = t & 63;
    const int lr = l & 15, lg = l >> 4;
    const int rowbase = (w * 16 + lr) * 256;
    const int swz = lr << 4;
    const int stride = gridDim.x;
    const bf16x8* cf = reinterpret_cast<const bf16x8*>(cfrag);
    const bf16x8* ef = reinterpret_cast<const bf16x8*>(efrag);

    int T = blockIdx.x;
    if (T >= ntiles) return;

    // ---- prologue: stage tile T into buf0 ----
    {
        const int base = T * 64;
        #pragma unroll
        for (int i = 0; i < 8; ++i) {
            int flat = i * 1024 + t * 4;
            int r = flat >> 7, k = flat & 127;
            float4 v = make_float4(0.f, 0.f, 0.f, 0.f);
            if (base + r < E) v = *reinterpret_cast<const float4*>(&e[(size_t)(base + r) * 128 + k]);
            ushort4 b;
            b.x = f2bf(v.x); b.y = f2bf(v.y); b.z = f2bf(v.z); b.w = f2bf(v.w);
            *reinterpret_cast<ushort4*>(lds[0] + r * 256 + ((k * 2) ^ ((r & 15) << 4))) = b;
        }
    }
    // indices + A-gathers for tile T
    int si[4], di[4];
    bool vld[4];
    u16 kA[4][4], qA[4][4];
    {
        const int base = T * 64;
        #pragma unroll
        for (int reg = 0; reg < 4; ++reg) {
            int ei = base + w * 16 + lg * 4 + reg;
            vld[reg] = ei < E;
            int ce = vld[reg] ? ei : (E - 1);
            si[reg] = src[ce];
            di[reg] = dst[ce];
        }
        #pragma unroll
        for (int n = 0; n < 4; ++n)
            #pragma unroll
            for (int reg = 0; reg < 4; ++reg) {
                kA[n][reg] = kbh[(size_t)si[reg] * 128 + n * 16 + lr];
                qA[n][reg] = qbh[(size_t)di[reg] * 128 + n * 16 + lr];
            }
    }

    int cur = 0;
    while (T < ntiles) {
        const int base = T * 64;
        const int Tn = T + stride;
        char* L = lds[cur];
        __syncthreads();                       // buf[cur] staged; prev buf reads done

        // A-fragments of e-tile
        bf16x8 afr[4];
        #pragma unroll
        for (int kk = 0; kk < 4; ++kk)
            afr[kk] = *reinterpret_cast<const bf16x8*>(L + rowbase + ((kk * 64 + lg * 16) ^ swz));

        // GEMM1: c_pre = e @ c_w.T
        f32x4 acc[8];
        #pragma unroll
        for (int n = 0; n < 8; ++n) acc[n] = (f32x4){0.f, 0.f, 0.f, 0.f};
        #pragma unroll
        for (int n = 0; n < 8; ++n)
            #pragma unroll
            for (int kk = 0; kk < 4; ++kk)
                acc[n] = __builtin_amdgcn_mfma_f32_16x16x32_bf16(afr[kk], cf[(n * 4 + kk) * 64 + l],
                                                                 acc[n], 0, 0, 0);

        // B-gathers (heads 4..7) for this tile: hide under epilogue A-half
        u16 kB[4][4], qB[4][4];
        #pragma unroll
        for (int n = 0; n < 4; ++n)
            #pragma unroll
            for (int reg = 0; reg < 4; ++reg) {
                kB[n][reg] = kbh[(size_t)si[reg] * 128 + (n + 4) * 16 + lr];
                qB[n][reg] = qbh[(size_t)di[reg] * 128 + (n + 4) * 16 + lr];
            }

        // epilogue: tanh -> score -> bf16 LDS (own rows); head-mean accum
        float macc[4] = {0.f, 0.f, 0.f, 0.f};
        #pragma unroll
        for (int n = 0; n < 8; ++n) {
            const int col = n * 16 + lr;
            const float cb = cbias[col];
            #pragma unroll
            for (int reg = 0; reg < 4; ++reg) {
                float kv = bf2f(n < 4 ? kA[n & 3][reg] : kB[n & 3][reg]);
                float qv = bf2f(n < 4 ? qA[n & 3][reg] : qB[n & 3][reg]);
                float sc = fast_tanh(acc[n][reg] + cb) * kv * qv;
                macc[reg] += sc;
                int row = w * 16 + lg * 4 + reg;
                *reinterpret_cast<u16*>(
                    L + row * 256 + ((col * 2) ^ ((row & 15) << 4))) = f2bf(sc);
            }
        }
        #pragma unroll
        for (int reg = 0; reg < 4; ++reg)
            if (vld[reg]) mean_out[(size_t)(base + w * 16 + lg * 4 + reg) * 16 + lr] = macc[reg] * 0.125f;

        // score A-fragments (in-wave LDS ordering)
        bf16x8 afr2[4];
        #pragma unroll
        for (int kk = 0; kk < 4; ++kk)
            afr2[kk] = *reinterpret_cast<const bf16x8*>(L + rowbase + ((kk * 64 + lg * 16) ^ swz));

        // logit via indicator-MFMA (frags rebuilt per-iter to limit live VGPR)
        {
            bf16x8 ind[4];
            #pragma unroll
            for (int kk = 0; kk < 4; ++kk)
                #pragma unroll
                for (int j = 0; j < 8; ++j)
                    ind[kk][j] = ((kk * 32 + lg * 8 + j) >> 4 == lr) ? (short)0x3F80 : (short)0;
            f32x4 lac = (f32x4){0.f, 0.f, 0.f, 0.f};
            #pragma unroll
            for (int kk = 0; kk < 4; ++kk)
                lac = __builtin_amdgcn_mfma_f32_16x16x32_bf16(afr2[kk], ind[kk], lac, 0, 0, 0);
            if (lr < 8) {
                #pragma unroll
                for (int reg = 0; reg < 4; ++reg)
                    if (vld[reg]) logit[(size_t)(base + w * 16 + lg * 4 + reg) * 8 + lr] = lac[reg] * ATTN_SCALE;
            }
        }

        // issue staging loads for tile Tn (consumed after GEMM2)
        float4 stg[8];
        if (Tn < ntiles) {
            const int nb = Tn * 64;
            #pragma unroll
            for (int i = 0; i < 8; ++i) {
                int flat = i * 1024 + t * 4;
                int r = flat >> 7, k = flat & 127;
                stg[i] = make_float4(0.f, 0.f, 0.f, 0.f);
                if (nb + r < E) stg[i] = *reinterpret_cast<const float4*>(&e[(size_t)(nb + r) * 128 + k]);
            }
        }

        // GEMM2 per-n: e_out = score @ eproj_w.T -> bf16 -> LDS (own rows)
        #pragma unroll
        for (int n = 0; n < 8; ++n) {
            f32x4 a2 = (f32x4){0.f, 0.f, 0.f, 0.f};
            #pragma unroll
            for (int kk = 0; kk < 4; ++kk)
                a2 = __builtin_amdgcn_mfma_f32_16x16x32_bf16(afr2[kk], ef[(n * 4 + kk) * 64 + l],
                                                             a2, 0, 0, 0);
            const int col = n * 16 + lr;
            const float eb = ebias[col];
            #pragma unroll
            for (int reg = 0; reg < 4; ++reg) {
                int row = w * 16 + lg * 4 + reg;
                *reinterpret_cast<u16*>(
                    L + row * 256 + ((col * 2) ^ ((row & 15) << 4))) = f2bf(a2[reg] + eb);
            }
        }
        // e_out coalesced stores from own rows
        #pragma unroll
        for (int rh = 0; rh < 2; ++rh) {
            #pragma unroll
            for (int ih = 0; ih < 2; ++ih) {
                int row = w * 16 + (l >> 3) + 8 * rh;
                int col = (l & 7) * 8 + 64 * ih;
                bf16x8 sv = *reinterpret_cast<const bf16x8*>(
                    L + row * 256 + ((col * 2) ^ ((row & 15) << 4)));
                float4 o0, o1;
                o0.x = bf2f((u16)sv[0]); o0.y = bf2f((u16)sv[1]);
                o0.z = bf2f((u16)sv[2]); o0.w = bf2f((u16)sv[3]);
                o1.x = bf2f((u16)sv[4]); o1.y = bf2f((u16)sv[5]);
                o1.z = bf2f((u16)sv[6]); o1.w = bf2f((u16)sv[7]);
                if (base + row < E) {
                    *reinterpret_cast<float4*>(&e_out[(size_t)(base + row) * 128 + col]) = o0;
                    *reinterpret_cast<float4*>(&e_out[(size_t)(base + row) * 128 + col + 4]) = o1;
                }
            }
        }

        // write staged tile into buf[cur^1]; prefetch indices + A-gathers for Tn
        if (Tn < ntiles) {
            char* Ln = lds[cur ^ 1];
            #pragma unroll
            for (int i = 0; i < 8; ++i) {
                int flat = i * 1024 + t * 4;
                int r = flat >> 7, k = flat & 127;
                ushort4 b;
                b.x = f2bf(stg[i].x); b.y = f2bf(stg[i].y);
                b.z = f2bf(stg[i].z); b.w = f2bf(stg[i].w);
                *reinterpret_cast<ushort4*>(Ln + r * 256 + ((k * 2) ^ ((r & 15) << 4))) = b;
            }
            const int nb = Tn * 64;
            #pragma unroll
            for (int reg = 0; reg < 4; ++reg) {
                int ei = nb + w * 16 + lg * 4 + reg;
                vld[reg] = ei < E;
                int ce = vld[reg] ? ei : (E - 1);
                si[reg] = src[ce];
                di[reg] = dst[ce];
            }
            #pragma unroll
            for (int n = 0; n < 4; ++n)
                #pragma unroll
                for (int reg = 0; reg < 4; ++reg) {
                    kA[n][reg] = kbh[(size_t)si[reg] * 128 + n * 16 + lr];
                    qA[n][reg] = qbh[(size_t)di[reg] * 128 + n * 16 + lr];
                }
        }
        T = Tn;
        cur ^= 1;
    }
}

// ---------- per-node softmax + aggregation ----------

__global__ __launch_bounds__(256) void node_kernel(
    const int* __restrict__ offsets, const int* __restrict__ eidx,
    const int* __restrict__ src, const float* __restrict__ logit,
    const u16* __restrict__ vbh, float* __restrict__ hagg, int N)
{
    __shared__ int   ls_src[4][64];
    __shared__ float ls_l[4][64][8];
    const int t = threadIdx.x, w = t >> 6, lane = t & 63;
    const int node = blockIdx.x * 4 + w;
    int off = 0, deg = 0;
    if (node < N) { off = offsets[node]; deg = offsets[node + 1] - off; }

    const int h = lane & 7, g = lane >> 3;
    float m = -3.0e38f, s = 0.f;

    for (int c0 = 0; c0 < deg; c0 += 64) {
        int cnt = min(64, deg - c0);
        if (lane < cnt) {
            int eid = eidx[off + c0 + lane];
            ls_src[w][lane] = src[eid];
            float4 l0 = *reinterpret_cast<const float4*>(&logit[(size_t)eid * 8]);
            float4 l1 = *reinterpret_cast<const float4*>(&logit[(size_t)eid * 8 + 4]);
            *reinterpret_cast<float4*>(&ls_l[w][lane][0]) = l0;
            *reinterpret_cast<float4*>(&ls_l[w][lane][4]) = l1;
        }
        __asm__ __volatile__("s_waitcnt lgkmcnt(0)" ::: "memory");
        float cm = -3.0e38f;
        for (int j = g; j < cnt; j += 8) cm = fmaxf(cm, ls_l[w][j][h]);
        cm = fmaxf(cm, __shfl_xor(cm, 8));
        cm = fmaxf(cm, __shfl_xor(cm, 16));
        cm = fmaxf(cm, __shfl_xor(cm, 32));
        float mn = fmaxf(m, cm);
        float cs = 0.f;
        for (int j = g; j < cnt; j += 8) cs += __expf(ls_l[w][j][h] - mn);
        cs += __shfl_xor(cs, 8); cs += __shfl_xor(cs, 16); cs += __shfl_xor(cs, 32);
        s = s * __expf(m - mn) + cs;
        m = mn;
    }
    float inv = (deg > 0) ? 1.f / s : 0.f;

    float a0 = 0.f, a1 = 0.f;
    const int d0 = lane, d1 = lane + 64, h0 = lane >> 4, h1 = 4 + h0;
    for (int c0 = 0; c0 < deg; c0 += 64) {
        int cnt = min(64, deg - c0);
        if (deg > 64 && lane < cnt) {
            int eid = eidx[off + c0 + lane];
            ls_src[w][lane] = src[eid];
            float4 l0 = *reinterpret_cast<const float4*>(&logit[(size_t)eid * 8]);
            float4 l1 = *reinterpret_cast<const float4*>(&logit[(size_t)eid * 8 + 4]);
            *reinterpret_cast<float4*>(&ls_l[w][lane][0]) = l0;
            *reinterpret_cast<float4*>(&ls_l[w][lane][4]) = l1;
        }
        __asm__ __volatile__("s_waitcnt lgkmcnt(0)" ::: "memory");
        for (int j = g; j < cnt; j += 8)
            ls_l[w][j][h] = __expf(ls_l[w][j][h] - m) * inv;
        __asm__ __volatile__("s_waitcnt lgkmcnt(0)" ::: "memory");
        #pragma unroll 4
        for (int j = 0; j < cnt; ++j) {
            int sn = ls_src[w][j];
            float w0 = ls_l[w][j][h0], w1 = ls_l[w][j][h1];
            a0 += w0 * bf2f(vbh[(size_t)sn * 128 + d0]);
            a1 += w1 * bf2f(vbh[(size_t)sn * 128 + d1]);
        }
    }
    if (node < N) {
        hagg[(size_t)node * 128 + d0] = a0;
        hagg[(size_t)node * 128 + d1] = a1;
    }
}

// ---------- launcher ----------

extern "C" void kernel_launch(void* const* d_in, const int* in_sizes, int n_in,
                              void* d_out, int out_size, void* d_ws, size_t ws_size,
                              hipStream_t stream)
{
    const float* h       = (const float*)d_in[0];
    const float* e       = (const float*)d_in[1];
    const int*   src     = (const int*)d_in[2];
    const int*   dst     = (const int*)d_in[3];
    const float* qkv_w   = (const float*)d_in[4];
    const float* qkv_b   = (const float*)d_in[5];
    const float* c_w     = (const float*)d_in[6];
    const float* c_b     = (const float*)d_in[7];
    const float* hproj_w = (const float*)d_in[8];
    const float* hproj_b = (const float*)d_in[9];
    const float* eproj_w = (const float*)d_in[10];
    const float* eproj_b = (const float*)d_in[11];

    const int N = in_sizes[0] / 128;
    const int E = in_sizes[1] / 128;

    float* h_out    = (float*)d_out;
    float* e_out    = h_out + (size_t)N * 128;
    float* mean_out = e_out + (size_t)E * 128;

    char* wp = (char*)d_ws;
    auto alloc = [&](size_t b) {
        void* p = (void*)wp;
        wp += (b + 255) & ~(size_t)255;
        return p;
    };
    short* qkvfrag = (short*)alloc(sizeof(short) * 3 * 2048 * 8);
    short* cfragb  = (short*)alloc(sizeof(short) * 2048 * 8);
    short* efragb  = (short*)alloc(sizeof(short) * 2048 * 8);
    short* hpfrag  = (short*)alloc(sizeof(short) * 2048 * 8);
    u16*   qbh     = (u16*)alloc(sizeof(u16) * (size_t)N * 128);
    u16*   kbh     = (u16*)alloc(sizeof(u16) * (size_t)N * 128);
    u16*   vbh     = (u16*)alloc(sizeof(u16) * (size_t)N * 128);
    float* hagg    = (float*)alloc(sizeof(float) * (size_t)N * 128);
    float* logit   = (float*)alloc(sizeof(float) * (size_t)E * 8);
    int*   counts  = (int*)alloc(sizeof(int) * (N + 1));
    int*   offs    = (int*)alloc(sizeof(int) * (N + 1));
    int*   cursor  = (int*)alloc(sizeof(int) * (N + 1));
    int*   stmp    = (int*)alloc(sizeof(int) * (N + 1));
    int*   bsum    = (int*)alloc(sizeof(int) * 64);
    int*   eidx    = (int*)alloc(sizeof(int) * E);

    hipMemsetAsync(counts, 0, sizeof(int) * (N + 1), stream);

    make_frag<<<8, 256, 0, stream>>>(qkv_w, qkvfrag);
    make_frag<<<8, 256, 0, stream>>>(qkv_w + 128 * 128, qkvfrag + 2048 * 8);
    make_frag<<<8, 256, 0, stream>>>(qkv_w + 2 * 128 * 128, qkvfrag + 2 * 2048 * 8);
    make_frag<<<8, 256, 0, stream>>>(c_w, cfragb);
    make_frag<<<8, 256, 0, stream>>>(eproj_w, efragb);
    make_frag<<<8, 256, 0, stream>>>(hproj_w, hpfrag);

    qkv_gemm<<<(N + 63) / 64, 256, 0, stream>>>(h, qkvfrag, qkv_b, qbh, kbh, vbh, N);

    hist_kernel<<<(E + 255) / 256, 256, 0, stream>>>(dst, counts, E);
    int nb = (N + 1023) / 1024;
    scan1<<<nb, 256, 0, stream>>>(counts, stmp, bsum, N);
    scan2<<<1, 64, 0, stream>>>(bsum, nb);
    scan3<<<(N + 255) / 256, 256, 0, stream>>>(stmp, bsum, offs, N);
    copy_kernel<<<(N + 256) / 256, 256, 0, stream>>>(offs, cursor, N + 1);
    scatter_kernel<<<(E + 255) / 256, 256, 0, stream>>>(dst, cursor, eidx, E);

    const int ntiles = (E + 63) / 64;
    const int egrid = ntiles < 1024 ? ntiles : 1024;
    edge_mfma<<<egrid, 256, 0, stream>>>(e, src, dst, cfragb, c_b, efragb,
                                         eproj_b, qbh, kbh, e_out, mean_out, logit, E, ntiles);

    node_kernel<<<(N + 3) / 4, 256, 0, stream>>>(offs, eidx, src, logit, vbh, hagg, N);

    gemm128<<<(N + 63) / 64, 256, 0, stream>>>(hagg, hpfrag, hproj_b, h_out, N);
}

// Round 8
// 488.626 us; speedup vs baseline: 1.3395x; 1.3395x over previous
//
#include <hip/hip_runtime.h>
#include <cmath>

typedef __attribute__((ext_vector_type(8))) short bf16x8;
typedef __attribute__((ext_vector_type(4))) float f32x4;
typedef unsigned short u16;

#define ATTN_SCALE 0.25f

__device__ inline u16 f2bf(float x) {
    union { float f; unsigned u; } v; v.f = x;
    unsigned r = v.u + 0x7FFFu + ((v.u >> 16) & 1u);
    return (u16)(r >> 16);
}
__device__ inline float bf2f(u16 u) {
    union { unsigned u; float f; } v; v.u = ((unsigned)u) << 16; return v.f;
}
__device__ inline float fast_tanh(float x) {
    float xc = fminf(fmaxf(x, -15.f), 15.f);
    float t = __expf(2.f * xc);
    return (t - 1.f) * __builtin_amdgcn_rcpf(t + 1.f);
}

// ---------- CSR build ----------

__global__ __launch_bounds__(256) void hist_kernel(const int* __restrict__ dst,
                                                   int* __restrict__ counts, int E) {
    int i = blockIdx.x * 256 + threadIdx.x;
    if (i < E) atomicAdd(&counts[dst[i]], 1);
}

__global__ __launch_bounds__(256) void scan1(const int* __restrict__ counts,
                                             int* __restrict__ tmp, int* __restrict__ bsum, int N) {
    __shared__ int wsum[4];
    int b = blockIdx.x, t = threadIdx.x;
    int base = b * 1024 + t * 4;
    int v0 = (base + 0 < N) ? counts[base + 0] : 0;
    int v1 = (base + 1 < N) ? counts[base + 1] : 0;
    int v2 = (base + 2 < N) ? counts[base + 2] : 0;
    int v3 = (base + 3 < N) ? counts[base + 3] : 0;
    int p0 = v0, p1 = p0 + v1, p2 = p1 + v2, p3 = p2 + v3;
    int s = p3;
    int lane = t & 63, wid = t >> 6;
    int sc = s;
    #pragma unroll
    for (int d = 1; d < 64; d <<= 1) {
        int o = __shfl_up(sc, d);
        if (lane >= d) sc += o;
    }
    if (lane == 63) wsum[wid] = sc;
    __syncthreads();
    int wof = 0;
    #pragma unroll
    for (int i = 0; i < 4; ++i) if (i < wid) wof += wsum[i];
    int excl = wof + sc - s;
    if (base + 0 < N) tmp[base + 0] = excl + p0;
    if (base + 1 < N) tmp[base + 1] = excl + p1;
    if (base + 2 < N) tmp[base + 2] = excl + p2;
    if (base + 3 < N) tmp[base + 3] = excl + p3;
    if (t == 255) bsum[b] = wof + sc;
}

__global__ void scan2(int* __restrict__ bsum, int nb) {
    int t = threadIdx.x;
    int v = (t < nb) ? bsum[t] : 0;
    int sc = v;
    #pragma unroll
    for (int d = 1; d < 64; d <<= 1) {
        int o = __shfl_up(sc, d);
        if (t >= d) sc += o;
    }
    if (t < nb) bsum[t] = sc - v;
}

__global__ __launch_bounds__(256) void scan3(const int* __restrict__ tmp,
                                             const int* __restrict__ bsum,
                                             int* __restrict__ offsets, int N) {
    int i = blockIdx.x * 256 + threadIdx.x;
    if (i < N) offsets[i + 1] = tmp[i] + bsum[i >> 10];
    if (i == 0) offsets[0] = 0;
}

__global__ __launch_bounds__(256) void copy_kernel(const int* __restrict__ a,
                                                   int* __restrict__ b, int n) {
    int i = blockIdx.x * 256 + threadIdx.x;
    if (i < n) b[i] = a[i];
}

__global__ __launch_bounds__(256) void scatter_kernel(const int* __restrict__ dst,
                                                      int* __restrict__ cursor,
                                                      int* __restrict__ eidx, int E) {
    int i = blockIdx.x * 256 + threadIdx.x;
    if (i < E) {
        int p = atomicAdd(&cursor[dst[i]], 1);
        eidx[p] = i;
    }
}

// ---------- weight -> MFMA B-fragment (bf16, frag-linear) ----------
__global__ __launch_bounds__(256) void make_frag(const float* __restrict__ W,
                                                 short* __restrict__ out) {
    int id = blockIdx.x * 256 + threadIdx.x;
    if (id >= 2048) return;
    int l = id & 63, t16 = id >> 6;
    int kk = t16 & 3, n = t16 >> 2;
    int col = n * 16 + (l & 15);
    int k0 = kk * 32 + (l >> 4) * 8;
    #pragma unroll
    for (int j = 0; j < 8; ++j)
        out[id * 8 + j] = (short)f2bf(W[col * 128 + k0 + j]);
}

// ---------- qkv GEMM: 3 channels, bf16 outputs ----------

__global__ __launch_bounds__(256) void qkv_gemm(
    const float* __restrict__ X, const short* __restrict__ frag,
    const float* __restrict__ bias,
    u16* __restrict__ Y0, u16* __restrict__ Y1, u16* __restrict__ Y2, int R)
{
    __shared__ __align__(16) char lds[64 * 256];
    const int t = threadIdx.x;
    const int base = blockIdx.x * 64;
    for (int i = 0; i < 8; ++i) {
        int flat = i * 1024 + t * 4;
        int r = flat >> 7, k = flat & 127;
        float4 v = make_float4(0.f, 0.f, 0.f, 0.f);
        if (base + r < R) v = *reinterpret_cast<const float4*>(&X[(size_t)(base + r) * 128 + k]);
        ushort4 b;
        b.x = f2bf(v.x); b.y = f2bf(v.y); b.z = f2bf(v.z); b.w = f2bf(v.w);
        *reinterpret_cast<ushort4*>(lds + r * 256 + ((k * 2) ^ ((r & 15) << 4))) = b;
    }
    __syncthreads();
    const int w = t >> 6, l = t & 63, lr = l & 15, lg = l >> 4;
    const int rowbase = (w * 16 + lr) * 256, swz = lr << 4;
    bf16x8 afr[4];
    #pragma unroll
    for (int kk = 0; kk < 4; ++kk)
        afr[kk] = *reinterpret_cast<const bf16x8*>(lds + rowbase + ((kk * 64 + lg * 16) ^ swz));
    for (int ch = 0; ch < 3; ++ch) {
        const bf16x8* bf = reinterpret_cast<const bf16x8*>(frag + ch * 2048 * 8);
        f32x4 acc[8];
        #pragma unroll
        for (int n = 0; n < 8; ++n) acc[n] = (f32x4){0.f, 0.f, 0.f, 0.f};
        #pragma unroll
        for (int n = 0; n < 8; ++n)
            #pragma unroll
            for (int kk = 0; kk < 4; ++kk)
                acc[n] = __builtin_amdgcn_mfma_f32_16x16x32_bf16(afr[kk], bf[(n * 4 + kk) * 64 + l],
                                                                 acc[n], 0, 0, 0);
        u16* Y = (ch == 0) ? Y0 : (ch == 1) ? Y1 : Y2;
        #pragma unroll
        for (int n = 0; n < 8; ++n) {
            int col = n * 16 + lr;
            float bv = bias[ch * 128 + col];
            #pragma unroll
            for (int reg = 0; reg < 4; ++reg) {
                int r = base + w * 16 + lg * 4 + reg;
                if (r < R) Y[(size_t)r * 128 + col] = f2bf(acc[n][reg] + bv);
            }
        }
    }
}

// ---------- generic rows x 128 @ 128x128 MFMA GEMM, f32 out (hproj) ----------

__global__ __launch_bounds__(256) void gemm128(
    const float* __restrict__ X, const short* __restrict__ frag,
    const float* __restrict__ bias, float* __restrict__ Y, int R)
{
    __shared__ __align__(16) char lds[64 * 256];
    const int t = threadIdx.x;
    const int base = blockIdx.x * 64;
    for (int i = 0; i < 8; ++i) {
        int flat = i * 1024 + t * 4;
        int r = flat >> 7, k = flat & 127;
        float4 v = make_float4(0.f, 0.f, 0.f, 0.f);
        if (base + r < R) v = *reinterpret_cast<const float4*>(&X[(size_t)(base + r) * 128 + k]);
        ushort4 b;
        b.x = f2bf(v.x); b.y = f2bf(v.y); b.z = f2bf(v.z); b.w = f2bf(v.w);
        *reinterpret_cast<ushort4*>(lds + r * 256 + ((k * 2) ^ ((r & 15) << 4))) = b;
    }
    __syncthreads();
    const int w = t >> 6, l = t & 63, lr = l & 15, lg = l >> 4;
    const int rowbase = (w * 16 + lr) * 256, swz = lr << 4;
    bf16x8 afr[4];
    #pragma unroll
    for (int kk = 0; kk < 4; ++kk)
        afr[kk] = *reinterpret_cast<const bf16x8*>(lds + rowbase + ((kk * 64 + lg * 16) ^ swz));
    const bf16x8* bf = reinterpret_cast<const bf16x8*>(frag);
    f32x4 acc[8];
    #pragma unroll
    for (int n = 0; n < 8; ++n) acc[n] = (f32x4){0.f, 0.f, 0.f, 0.f};
    #pragma unroll
    for (int n = 0; n < 8; ++n)
        #pragma unroll
        for (int kk = 0; kk < 4; ++kk)
            acc[n] = __builtin_amdgcn_mfma_f32_16x16x32_bf16(afr[kk], bf[(n * 4 + kk) * 64 + l],
                                                             acc[n], 0, 0, 0);
    #pragma unroll
    for (int n = 0; n < 8; ++n) {
        int col = n * 16 + lr;
        float bv = bias[col];
        #pragma unroll
        for (int reg = 0; reg < 4; ++reg) {
            int r = base + w * 16 + lg * 4 + reg;
            if (r < R) Y[(size_t)r * 128 + col] = acc[n][reg] + bv;
        }
    }
}

// ---------- fused edge kernel (R6 structure, n-halved to cut VGPR liveness) ----------
// One tile per block (R7 persistent version: VGPR 256, −46% — reverted).
// GEMM1/epilogue split in two 4-head halves so only {afr, one acc half,
// one gather batch} are live at once.

__global__ __launch_bounds__(256) void edge_mfma(
    const float* __restrict__ e, const int* __restrict__ src, const int* __restrict__ dst,
    const short* __restrict__ cfrag, const float* __restrict__ cbias,
    const short* __restrict__ efrag, const float* __restrict__ ebias,
    const u16* __restrict__ qbh, const u16* __restrict__ kbh,
    float* __restrict__ e_out, float* __restrict__ mean_out,
    float* __restrict__ logit, int E)
{
    __shared__ __align__(16) char lds[64 * 256];
    const int t = threadIdx.x;
    const int base = blockIdx.x * 64;

    // stage e tile as bf16, swizzled: byte ^= (row&15)<<4
    for (int i = 0; i < 8; ++i) {
        int flat = i * 1024 + t * 4;
        int r = flat >> 7, k = flat & 127;
        float4 v = make_float4(0.f, 0.f, 0.f, 0.f);
        if (base + r < E) v = *reinterpret_cast<const float4*>(&e[(size_t)(base + r) * 128 + k]);
        ushort4 b;
        b.x = f2bf(v.x); b.y = f2bf(v.y); b.z = f2bf(v.z); b.w = f2bf(v.w);
        *reinterpret_cast<ushort4*>(lds + r * 256 + ((k * 2) ^ ((r & 15) << 4))) = b;
    }

    const int w = t >> 6, l = t & 63;
    const int lr = l & 15, lg = l >> 4;
    const int rowbase = (w * 16 + lr) * 256;
    const int swz = lr << 4;

    // edge ids + indices (independent of LDS)
    int er[4], si[4], di[4];
    bool vld[4];
    #pragma unroll
    for (int reg = 0; reg < 4; ++reg) {
        int ei = base + w * 16 + lg * 4 + reg;
        vld[reg] = ei < E;
        int ce = vld[reg] ? ei : (E - 1);
        er[reg] = ei;
        si[reg] = src[ce];
        di[reg] = dst[ce];
    }
    // prefetch batch A (heads 0..3): latency hides under staging drain + barrier
    u16 kA[4][4], qA[4][4];
    #pragma unroll
    for (int n = 0; n < 4; ++n)
        #pragma unroll
        for (int reg = 0; reg < 4; ++reg) {
            kA[n][reg] = kbh[(size_t)si[reg] * 128 + n * 16 + lr];
            qA[n][reg] = qbh[(size_t)di[reg] * 128 + n * 16 + lr];
        }

    __syncthreads();

    bf16x8 afr[4];
    #pragma unroll
    for (int kk = 0; kk < 4; ++kk)
        afr[kk] = *reinterpret_cast<const bf16x8*>(lds + rowbase + ((kk * 64 + lg * 16) ^ swz));

    const bf16x8* cf = reinterpret_cast<const bf16x8*>(cfrag);
    float macc[4] = {0.f, 0.f, 0.f, 0.f};

    // ---- half A: GEMM1 n=0..3, then epilogue consuming kA/qA ----
    {
        f32x4 accA[4];
        #pragma unroll
        for (int n = 0; n < 4; ++n) accA[n] = (f32x4){0.f, 0.f, 0.f, 0.f};
        #pragma unroll
        for (int n = 0; n < 4; ++n)
            #pragma unroll
            for (int kk = 0; kk < 4; ++kk)
                accA[n] = __builtin_amdgcn_mfma_f32_16x16x32_bf16(afr[kk], cf[(n * 4 + kk) * 64 + l],
                                                                  accA[n], 0, 0, 0);
        #pragma unroll
        for (int n = 0; n < 4; ++n) {
            const int col = n * 16 + lr;
            const float cb = cbias[col];
            #pragma unroll
            for (int reg = 0; reg < 4; ++reg) {
                float sc = fast_tanh(accA[n][reg] + cb) * bf2f(kA[n][reg]) * bf2f(qA[n][reg]);
                macc[reg] += sc;
                int row = w * 16 + lg * 4 + reg;
                *reinterpret_cast<u16*>(
                    lds + row * 256 + ((col * 2) ^ ((row & 15) << 4))) = f2bf(sc);
            }
        }
    }

    // prefetch batch B (heads 4..7): hides under half-A epilogue & half-B GEMM
    u16 kB[4][4], qB[4][4];
    #pragma unroll
    for (int n = 0; n < 4; ++n)
        #pragma unroll
        for (int reg = 0; reg < 4; ++reg) {
            kB[n][reg] = kbh[(size_t)si[reg] * 128 + (n + 4) * 16 + lr];
            qB[n][reg] = qbh[(size_t)di[reg] * 128 + (n + 4) * 16 + lr];
        }

    // ---- half B: GEMM1 n=4..7, epilogue consuming kB/qB ----
    {
        f32x4 accB[4];
        #pragma unroll
        for (int n = 0; n < 4; ++n) accB[n] = (f32x4){0.f, 0.f, 0.f, 0.f};
        #pragma unroll
        for (int n = 0; n < 4; ++n)
            #pragma unroll
            for (int kk = 0; kk < 4; ++kk)
                accB[n] = __builtin_amdgcn_mfma_f32_16x16x32_bf16(afr[kk], cf[((n + 4) * 4 + kk) * 64 + l],
                                                                  accB[n], 0, 0, 0);
        #pragma unroll
        for (int n = 0; n < 4; ++n) {
            const int col = (n + 4) * 16 + lr;
            const float cb = cbias[col];
            #pragma unroll
            for (int reg = 0; reg < 4; ++reg) {
                float sc = fast_tanh(accB[n][reg] + cb) * bf2f(kB[n][reg]) * bf2f(qB[n][reg]);
                macc[reg] += sc;
                int row = w * 16 + lg * 4 + reg;
                *reinterpret_cast<u16*>(
                    lds + row * 256 + ((col * 2) ^ ((row & 15) << 4))) = f2bf(sc);
            }
        }
    }
    #pragma unroll
    for (int reg = 0; reg < 4; ++reg)
        if (vld[reg]) mean_out[(size_t)er[reg] * 16 + lr] = macc[reg] * 0.125f;

    // A-frags from score (in-wave LDS ordering)
    bf16x8 afr2[4];
    #pragma unroll
    for (int kk = 0; kk < 4; ++kk)
        afr2[kk] = *reinterpret_cast<const bf16x8*>(lds + rowbase + ((kk * 64 + lg * 16) ^ swz));

    // logit via indicator-MFMA: B[k][h] = (k>>4 == h); LINEAR store by edge id
    {
        bf16x8 ind[4];
        #pragma unroll
        for (int kk = 0; kk < 4; ++kk)
            #pragma unroll
            for (int j = 0; j < 8; ++j)
                ind[kk][j] = ((kk * 32 + lg * 8 + j) >> 4 == lr) ? (short)0x3F80 : (short)0;
        f32x4 lac = (f32x4){0.f, 0.f, 0.f, 0.f};
        #pragma unroll
        for (int kk = 0; kk < 4; ++kk)
            lac = __builtin_amdgcn_mfma_f32_16x16x32_bf16(afr2[kk], ind[kk], lac, 0, 0, 0);
        if (lr < 8) {
            #pragma unroll
            for (int reg = 0; reg < 4; ++reg)
                if (vld[reg]) logit[(size_t)er[reg] * 8 + lr] = lac[reg] * ATTN_SCALE;
        }
    }

    // GEMM2 per-n: e_out = score @ eproj_w.T -> bf16 -> LDS (own rows)
    const bf16x8* ef = reinterpret_cast<const bf16x8*>(efrag);
    #pragma unroll
    for (int n = 0; n < 8; ++n) {
        f32x4 a2 = (f32x4){0.f, 0.f, 0.f, 0.f};
        #pragma unroll
        for (int kk = 0; kk < 4; ++kk)
            a2 = __builtin_amdgcn_mfma_f32_16x16x32_bf16(afr2[kk], ef[(n * 4 + kk) * 64 + l],
                                                         a2, 0, 0, 0);
        const int col = n * 16 + lr;
        const float eb = ebias[col];
        #pragma unroll
        for (int reg = 0; reg < 4; ++reg) {
            int row = w * 16 + lg * 4 + reg;
            *reinterpret_cast<u16*>(
                lds + row * 256 + ((col * 2) ^ ((row & 15) << 4))) = f2bf(a2[reg] + eb);
        }
    }
    // e_out coalesced stores from own rows
    #pragma unroll
    for (int rh = 0; rh < 2; ++rh) {
        #pragma unroll
        for (int ih = 0; ih < 2; ++ih) {
            int row = w * 16 + (l >> 3) + 8 * rh;
            int col = (l & 7) * 8 + 64 * ih;
            bf16x8 sv = *reinterpret_cast<const bf16x8*>(
                lds + row * 256 + ((col * 2) ^ ((row & 15) << 4)));
            float4 o0, o1;
            o0.x = bf2f((u16)sv[0]); o0.y = bf2f((u16)sv[1]);
            o0.z = bf2f((u16)sv[2]); o0.w = bf2f((u16)sv[3]);
            o1.x = bf2f((u16)sv[4]); o1.y = bf2f((u16)sv[5]);
            o1.z = bf2f((u16)sv[6]); o1.w = bf2f((u16)sv[7]);
            if (base + row < E) {
                *reinterpret_cast<float4*>(&e_out[(size_t)(base + row) * 128 + col]) = o0;
                *reinterpret_cast<float4*>(&e_out[(size_t)(base + row) * 128 + col + 4]) = o1;
            }
        }
    }
}

// ---------- per-node softmax + aggregation ----------

__global__ __launch_bounds__(256) void node_kernel(
    const int* __restrict__ offsets, const int* __restrict__ eidx,
    const int* __restrict__ src, const float* __restrict__ logit,
    const u16* __restrict__ vbh, float* __restrict__ hagg, int N)
{
    __shared__ int   ls_src[4][64];
    __shared__ float ls_l[4][64][8];
    const int t = threadIdx.x, w = t >> 6, lane = t & 63;
    const int node = blockIdx.x * 4 + w;
    int off = 0, deg = 0;
    if (node < N) { off = offsets[node]; deg = offsets[node + 1] - off; }

    const int h = lane & 7, g = lane >> 3;
    float m = -3.0e38f, s = 0.f;

    for (int c0 = 0; c0 < deg; c0 += 64) {
        int cnt = min(64, deg - c0);
        if (lane < cnt) {
            int eid = eidx[off + c0 + lane];
            ls_src[w][lane] = src[eid];
            float4 l0 = *reinterpret_cast<const float4*>(&logit[(size_t)eid * 8]);
            float4 l1 = *reinterpret_cast<const float4*>(&logit[(size_t)eid * 8 + 4]);
            *reinterpret_cast<float4*>(&ls_l[w][lane][0]) = l0;
            *reinterpret_cast<float4*>(&ls_l[w][lane][4]) = l1;
        }
        __asm__ __volatile__("s_waitcnt lgkmcnt(0)" ::: "memory");
        float cm = -3.0e38f;
        for (int j = g; j < cnt; j += 8) cm = fmaxf(cm, ls_l[w][j][h]);
        cm = fmaxf(cm, __shfl_xor(cm, 8));
        cm = fmaxf(cm, __shfl_xor(cm, 16));
        cm = fmaxf(cm, __shfl_xor(cm, 32));
        float mn = fmaxf(m, cm);
        float cs = 0.f;
        for (int j = g; j < cnt; j += 8) cs += __expf(ls_l[w][j][h] - mn);
        cs += __shfl_xor(cs, 8); cs += __shfl_xor(cs, 16); cs += __shfl_xor(cs, 32);
        s = s * __expf(m - mn) + cs;
        m = mn;
    }
    float inv = (deg > 0) ? 1.f / s : 0.f;

    float a0 = 0.f, a1 = 0.f;
    const int d0 = lane, d1 = lane + 64, h0 = lane >> 4, h1 = 4 + h0;
    for (int c0 = 0; c0 < deg; c0 += 64) {
        int cnt = min(64, deg - c0);
        if (deg > 64 && lane < cnt) {
            int eid = eidx[off + c0 + lane];
            ls_src[w][lane] = src[eid];
            float4 l0 = *reinterpret_cast<const float4*>(&logit[(size_t)eid * 8]);
            float4 l1 = *reinterpret_cast<const float4*>(&logit[(size_t)eid * 8 + 4]);
            *reinterpret_cast<float4*>(&ls_l[w][lane][0]) = l0;
            *reinterpret_cast<float4*>(&ls_l[w][lane][4]) = l1;
        }
        __asm__ __volatile__("s_waitcnt lgkmcnt(0)" ::: "memory");
        for (int j = g; j < cnt; j += 8)
            ls_l[w][j][h] = __expf(ls_l[w][j][h] - m) * inv;
        __asm__ __volatile__("s_waitcnt lgkmcnt(0)" ::: "memory");
        #pragma unroll 4
        for (int j = 0; j < cnt; ++j) {
            int sn = ls_src[w][j];
            float w0 = ls_l[w][j][h0], w1 = ls_l[w][j][h1];
            a0 += w0 * bf2f(vbh[(size_t)sn * 128 + d0]);
            a1 += w1 * bf2f(vbh[(size_t)sn * 128 + d1]);
        }
    }
    if (node < N) {
        hagg[(size_t)node * 128 + d0] = a0;
        hagg[(size_t)node * 128 + d1] = a1;
    }
}

// ---------- launcher ----------

extern "C" void kernel_launch(void* const* d_in, const int* in_sizes, int n_in,
                              void* d_out, int out_size, void* d_ws, size_t ws_size,
                              hipStream_t stream)
{
    const float* h       = (const float*)d_in[0];
    const float* e       = (const float*)d_in[1];
    const int*   src     = (const int*)d_in[2];
    const int*   dst     = (const int*)d_in[3];
    const float* qkv_w   = (const float*)d_in[4];
    const float* qkv_b   = (const float*)d_in[5];
    const float* c_w     = (const float*)d_in[6];
    const float* c_b     = (const float*)d_in[7];
    const float* hproj_w = (const float*)d_in[8];
    const float* hproj_b = (const float*)d_in[9];
    const float* eproj_w = (const float*)d_in[10];
    const float* eproj_b = (const float*)d_in[11];

    const int N = in_sizes[0] / 128;
    const int E = in_sizes[1] / 128;

    float* h_out    = (float*)d_out;
    float* e_out    = h_out + (size_t)N * 128;
    float* mean_out = e_out + (size_t)E * 128;

    char* wp = (char*)d_ws;
    auto alloc = [&](size_t b) {
        void* p = (void*)wp;
        wp += (b + 255) & ~(size_t)255;
        return p;
    };
    short* qkvfrag = (short*)alloc(sizeof(short) * 3 * 2048 * 8);
    short* cfragb  = (short*)alloc(sizeof(short) * 2048 * 8);
    short* efragb  = (short*)alloc(sizeof(short) * 2048 * 8);
    short* hpfrag  = (short*)alloc(sizeof(short) * 2048 * 8);
    u16*   qbh     = (u16*)alloc(sizeof(u16) * (size_t)N * 128);
    u16*   kbh     = (u16*)alloc(sizeof(u16) * (size_t)N * 128);
    u16*   vbh     = (u16*)alloc(sizeof(u16) * (size_t)N * 128);
    float* hagg    = (float*)alloc(sizeof(float) * (size_t)N * 128);
    float* logit   = (float*)alloc(sizeof(float) * (size_t)E * 8);
    int*   counts  = (int*)alloc(sizeof(int) * (N + 1));
    int*   offs    = (int*)alloc(sizeof(int) * (N + 1));
    int*   cursor  = (int*)alloc(sizeof(int) * (N + 1));
    int*   stmp    = (int*)alloc(sizeof(int) * (N + 1));
    int*   bsum    = (int*)alloc(sizeof(int) * 64);
    int*   eidx    = (int*)alloc(sizeof(int) * E);

    hipMemsetAsync(counts, 0, sizeof(int) * (N + 1), stream);

    make_frag<<<8, 256, 0, stream>>>(qkv_w, qkvfrag);
    make_frag<<<8, 256, 0, stream>>>(qkv_w + 128 * 128, qkvfrag + 2048 * 8);
    make_frag<<<8, 256, 0, stream>>>(qkv_w + 2 * 128 * 128, qkvfrag + 2 * 2048 * 8);
    make_frag<<<8, 256, 0, stream>>>(c_w, cfragb);
    make_frag<<<8, 256, 0, stream>>>(eproj_w, efragb);
    make_frag<<<8, 256, 0, stream>>>(hproj_w, hpfrag);

    qkv_gemm<<<(N + 63) / 64, 256, 0, stream>>>(h, qkvfrag, qkv_b, qbh, kbh, vbh, N);

    hist_kernel<<<(E + 255) / 256, 256, 0, stream>>>(dst, counts, E);
    int nb = (N + 1023) / 1024;
    scan1<<<nb, 256, 0, stream>>>(counts, stmp, bsum, N);
    scan2<<<1, 64, 0, stream>>>(bsum, nb);
    scan3<<<(N + 255) / 256, 256, 0, stream>>>(stmp, bsum, offs, N);
    copy_kernel<<<(N + 256) / 256, 256, 0, stream>>>(offs, cursor, N + 1);
    scatter_kernel<<<(E + 255) / 256, 256, 0, stream>>>(dst, cursor, eidx, E);

    edge_mfma<<<(E + 63) / 64, 256, 0, stream>>>(e, src, dst, cfragb, c_b, efragb,
                                                 eproj_b, qbh, kbh, e_out, mean_out, logit, E);

    node_kernel<<<(N + 3) / 4, 256, 0, stream>>>(offs, eidx, src, logit, vbh, hagg, N);

    gemm128<<<(N + 63) / 64, 256, 0, stream>>>(hagg, hpfrag, hproj_b, h_out, N);
}

// Round 9
// 480.469 us; speedup vs baseline: 1.3622x; 1.0170x over previous
//
#include <hip/hip_runtime.h>
#include <cmath>

typedef __attribute__((ext_vector_type(8))) short bf16x8;
typedef __attribute__((ext_vector_type(4))) float f32x4;
typedef __attribute__((ext_vector_type(4))) unsigned short u16x4;
typedef __attribute__((ext_vector_type(8))) unsigned short u16x8;
typedef unsigned short u16;

#define ATTN_SCALE 0.25f

__device__ inline u16 f2bf(float x) {
    union { float f; unsigned u; } v; v.f = x;
    unsigned r = v.u + 0x7FFFu + ((v.u >> 16) & 1u);
    return (u16)(r >> 16);
}
__device__ inline float bf2f(u16 u) {
    union { unsigned u; float f; } v; v.u = ((unsigned)u) << 16; return v.f;
}
__device__ inline float fast_tanh(float x) {
    float xc = fminf(fmaxf(x, -15.f), 15.f);
    float t = __expf(2.f * xc);
    return (t - 1.f) * __builtin_amdgcn_rcpf(t + 1.f);
}

// ---------- CSR build ----------

__global__ __launch_bounds__(256) void hist_kernel(const int* __restrict__ dst,
                                                   int* __restrict__ counts, int E) {
    int i = blockIdx.x * 256 + threadIdx.x;
    if (i < E) atomicAdd(&counts[dst[i]], 1);
}

__global__ __launch_bounds__(256) void scan1(const int* __restrict__ counts,
                                             int* __restrict__ tmp, int* __restrict__ bsum, int N) {
    __shared__ int wsum[4];
    int b = blockIdx.x, t = threadIdx.x;
    int base = b * 1024 + t * 4;
    int v0 = (base + 0 < N) ? counts[base + 0] : 0;
    int v1 = (base + 1 < N) ? counts[base + 1] : 0;
    int v2 = (base + 2 < N) ? counts[base + 2] : 0;
    int v3 = (base + 3 < N) ? counts[base + 3] : 0;
    int p0 = v0, p1 = p0 + v1, p2 = p1 + v2, p3 = p2 + v3;
    int s = p3;
    int lane = t & 63, wid = t >> 6;
    int sc = s;
    #pragma unroll
    for (int d = 1; d < 64; d <<= 1) {
        int o = __shfl_up(sc, d);
        if (lane >= d) sc += o;
    }
    if (lane == 63) wsum[wid] = sc;
    __syncthreads();
    int wof = 0;
    #pragma unroll
    for (int i = 0; i < 4; ++i) if (i < wid) wof += wsum[i];
    int excl = wof + sc - s;
    if (base + 0 < N) tmp[base + 0] = excl + p0;
    if (base + 1 < N) tmp[base + 1] = excl + p1;
    if (base + 2 < N) tmp[base + 2] = excl + p2;
    if (base + 3 < N) tmp[base + 3] = excl + p3;
    if (t == 255) bsum[b] = wof + sc;
}

__global__ void scan2(int* __restrict__ bsum, int nb) {
    int t = threadIdx.x;
    int v = (t < nb) ? bsum[t] : 0;
    int sc = v;
    #pragma unroll
    for (int d = 1; d < 64; d <<= 1) {
        int o = __shfl_up(sc, d);
        if (t >= d) sc += o;
    }
    if (t < nb) bsum[t] = sc - v;
}

__global__ __launch_bounds__(256) void scan3(const int* __restrict__ tmp,
                                             const int* __restrict__ bsum,
                                             int* __restrict__ offsets, int N) {
    int i = blockIdx.x * 256 + threadIdx.x;
    if (i < N) offsets[i + 1] = tmp[i] + bsum[i >> 10];
    if (i == 0) offsets[0] = 0;
}

__global__ __launch_bounds__(256) void copy_kernel(const int* __restrict__ a,
                                                   int* __restrict__ b, int n) {
    int i = blockIdx.x * 256 + threadIdx.x;
    if (i < n) b[i] = a[i];
}

__global__ __launch_bounds__(256) void scatter_kernel(const int* __restrict__ dst,
                                                      int* __restrict__ cursor,
                                                      int* __restrict__ eidx, int E) {
    int i = blockIdx.x * 256 + threadIdx.x;
    if (i < E) {
        int p = atomicAdd(&cursor[dst[i]], 1);
        eidx[p] = i;
    }
}

// ---------- weight -> MFMA B-fragment (bf16, frag-linear) ----------
__global__ __launch_bounds__(256) void make_frag(const float* __restrict__ W,
                                                 short* __restrict__ out) {
    int id = blockIdx.x * 256 + threadIdx.x;
    if (id >= 2048) return;
    int l = id & 63, t16 = id >> 6;
    int kk = t16 & 3, n = t16 >> 2;
    int col = n * 16 + (l & 15);
    int k0 = kk * 32 + (l >> 4) * 8;
    #pragma unroll
    for (int j = 0; j < 8; ++j)
        out[id * 8 + j] = (short)f2bf(W[col * 128 + k0 + j]);
}

// ---------- qkv GEMM: q,k -> dim-major packed bf16 [node][d16][head]; v standard ----------

__global__ __launch_bounds__(256) void qkv_gemm(
    const float* __restrict__ X, const short* __restrict__ frag,
    const float* __restrict__ bias,
    u16* __restrict__ Yq, u16* __restrict__ Yk, u16* __restrict__ Yv, int R)
{
    __shared__ __align__(16) char lds[64 * 256];
    const int t = threadIdx.x;
    const int base = blockIdx.x * 64;
    for (int i = 0; i < 8; ++i) {
        int flat = i * 1024 + t * 4;
        int r = flat >> 7, k = flat & 127;
        float4 v = make_float4(0.f, 0.f, 0.f, 0.f);
        if (base + r < R) v = *reinterpret_cast<const float4*>(&X[(size_t)(base + r) * 128 + k]);
        ushort4 b;
        b.x = f2bf(v.x); b.y = f2bf(v.y); b.z = f2bf(v.z); b.w = f2bf(v.w);
        *reinterpret_cast<ushort4*>(lds + r * 256 + ((k * 2) ^ ((r & 15) << 4))) = b;
    }
    __syncthreads();
    const int w = t >> 6, l = t & 63, lr = l & 15, lg = l >> 4;
    const int rowbase = (w * 16 + lr) * 256, swz = lr << 4;
    bf16x8 afr[4];
    #pragma unroll
    for (int kk = 0; kk < 4; ++kk)
        afr[kk] = *reinterpret_cast<const bf16x8*>(lds + rowbase + ((kk * 64 + lg * 16) ^ swz));
    for (int ch = 0; ch < 3; ++ch) {
        const bf16x8* bf = reinterpret_cast<const bf16x8*>(frag + ch * 2048 * 8);
        f32x4 acc[8];
        #pragma unroll
        for (int n = 0; n < 8; ++n) acc[n] = (f32x4){0.f, 0.f, 0.f, 0.f};
        #pragma unroll
        for (int n = 0; n < 8; ++n)
            #pragma unroll
            for (int kk = 0; kk < 4; ++kk)
                acc[n] = __builtin_amdgcn_mfma_f32_16x16x32_bf16(afr[kk], bf[(n * 4 + kk) * 64 + l],
                                                                 acc[n], 0, 0, 0);
        if (ch < 2) {
            // dim-major packed: Y[r*128 + lr*8 + n], one 16B store per reg-row
            u16* Y = (ch == 0) ? Yq : Yk;
            float bv[8];
            #pragma unroll
            for (int n = 0; n < 8; ++n) bv[n] = bias[ch * 128 + n * 16 + lr];
            #pragma unroll
            for (int reg = 0; reg < 4; ++reg) {
                int r = base + w * 16 + lg * 4 + reg;
                if (r < R) {
                    u16x8 pk;
                    #pragma unroll
                    for (int n = 0; n < 8; ++n) pk[n] = f2bf(acc[n][reg] + bv[n]);
                    *reinterpret_cast<u16x8*>(&Y[(size_t)r * 128 + lr * 8]) = pk;
                }
            }
        } else {
            #pragma unroll
            for (int n = 0; n < 8; ++n) {
                int col = n * 16 + lr;
                float bv = bias[ch * 128 + col];
                #pragma unroll
                for (int reg = 0; reg < 4; ++reg) {
                    int r = base + w * 16 + lg * 4 + reg;
                    if (r < R) Yv[(size_t)r * 128 + col] = f2bf(acc[n][reg] + bv);
                }
            }
        }
    }
}

// ---------- generic rows x 128 @ 128x128 MFMA GEMM, f32 out (hproj) ----------

__global__ __launch_bounds__(256) void gemm128(
    const float* __restrict__ X, const short* __restrict__ frag,
    const float* __restrict__ bias, float* __restrict__ Y, int R)
{
    __shared__ __align__(16) char lds[64 * 256];
    const int t = threadIdx.x;
    const int base = blockIdx.x * 64;
    for (int i = 0; i < 8; ++i) {
        int flat = i * 1024 + t * 4;
        int r = flat >> 7, k = flat & 127;
        float4 v = make_float4(0.f, 0.f, 0.f, 0.f);
        if (base + r < R) v = *reinterpret_cast<const float4*>(&X[(size_t)(base + r) * 128 + k]);
        ushort4 b;
        b.x = f2bf(v.x); b.y = f2bf(v.y); b.z = f2bf(v.z); b.w = f2bf(v.w);
        *reinterpret_cast<ushort4*>(lds + r * 256 + ((k * 2) ^ ((r & 15) << 4))) = b;
    }
    __syncthreads();
    const int w = t >> 6, l = t & 63, lr = l & 15, lg = l >> 4;
    const int rowbase = (w * 16 + lr) * 256, swz = lr << 4;
    bf16x8 afr[4];
    #pragma unroll
    for (int kk = 0; kk < 4; ++kk)
        afr[kk] = *reinterpret_cast<const bf16x8*>(lds + rowbase + ((kk * 64 + lg * 16) ^ swz));
    const bf16x8* bf = reinterpret_cast<const bf16x8*>(frag);
    f32x4 acc[8];
    #pragma unroll
    for (int n = 0; n < 8; ++n) acc[n] = (f32x4){0.f, 0.f, 0.f, 0.f};
    #pragma unroll
    for (int n = 0; n < 8; ++n)
        #pragma unroll
        for (int kk = 0; kk < 4; ++kk)
            acc[n] = __builtin_amdgcn_mfma_f32_16x16x32_bf16(afr[kk], bf[(n * 4 + kk) * 64 + l],
                                                             acc[n], 0, 0, 0);
    #pragma unroll
    for (int n = 0; n < 8; ++n) {
        int col = n * 16 + lr;
        float bv = bias[col];
        #pragma unroll
        for (int reg = 0; reg < 4; ++reg) {
            int r = base + w * 16 + lg * 4 + reg;
            if (r < R) Y[(size_t)r * 128 + col] = acc[n][reg] + bv;
        }
    }
}

// ---------- fused edge kernel (packed dim-major q/k gathers, n-halved) ----------
// q/k layout [node][d16][head]: gather = one 8B load per (edge-reg, op, half);
// a 16-lane group (fixed lg,reg) reads 128B contiguous of one node row.
// Gather reg state: 16 VGPR per half (vs 64 scalar-gather regs in R8).

__global__ __launch_bounds__(256) void edge_mfma(
    const float* __restrict__ e, const int* __restrict__ src, const int* __restrict__ dst,
    const short* __restrict__ cfrag, const float* __restrict__ cbias,
    const short* __restrict__ efrag, const float* __restrict__ ebias,
    const u16* __restrict__ qbh, const u16* __restrict__ kbh,
    float* __restrict__ e_out, float* __restrict__ mean_out,
    float* __restrict__ logit, int E)
{
    __shared__ __align__(16) char lds[64 * 256];
    const int t = threadIdx.x;
    const int base = blockIdx.x * 64;

    // stage e tile as bf16, swizzled: byte ^= (row&15)<<4
    for (int i = 0; i < 8; ++i) {
        int flat = i * 1024 + t * 4;
        int r = flat >> 7, k = flat & 127;
        float4 v = make_float4(0.f, 0.f, 0.f, 0.f);
        if (base + r < E) v = *reinterpret_cast<const float4*>(&e[(size_t)(base + r) * 128 + k]);
        ushort4 b;
        b.x = f2bf(v.x); b.y = f2bf(v.y); b.z = f2bf(v.z); b.w = f2bf(v.w);
        *reinterpret_cast<ushort4*>(lds + r * 256 + ((k * 2) ^ ((r & 15) << 4))) = b;
    }

    const int w = t >> 6, l = t & 63;
    const int lr = l & 15, lg = l >> 4;
    const int rowbase = (w * 16 + lr) * 256;
    const int swz = lr << 4;

    int si[4], di[4];
    bool vld[4];
    #pragma unroll
    for (int reg = 0; reg < 4; ++reg) {
        int ei = base + w * 16 + lg * 4 + reg;
        vld[reg] = ei < E;
        int ce = vld[reg] ? ei : (E - 1);
        si[reg] = src[ce];
        di[reg] = dst[ce];
    }
    // gather batch A (heads 0..3): one 8B load per reg per operand
    u16x4 kA[4], qA[4];
    #pragma unroll
    for (int reg = 0; reg < 4; ++reg) {
        kA[reg] = *reinterpret_cast<const u16x4*>(&kbh[(size_t)si[reg] * 128 + lr * 8]);
        qA[reg] = *reinterpret_cast<const u16x4*>(&qbh[(size_t)di[reg] * 128 + lr * 8]);
    }

    __syncthreads();

    bf16x8 afr[4];
    #pragma unroll
    for (int kk = 0; kk < 4; ++kk)
        afr[kk] = *reinterpret_cast<const bf16x8*>(lds + rowbase + ((kk * 64 + lg * 16) ^ swz));

    const bf16x8* cf = reinterpret_cast<const bf16x8*>(cfrag);
    float macc[4] = {0.f, 0.f, 0.f, 0.f};

    // ---- half A: GEMM1 n=0..3 + epilogue ----
    {
        f32x4 accA[4];
        #pragma unroll
        for (int n = 0; n < 4; ++n) accA[n] = (f32x4){0.f, 0.f, 0.f, 0.f};
        #pragma unroll
        for (int n = 0; n < 4; ++n)
            #pragma unroll
            for (int kk = 0; kk < 4; ++kk)
                accA[n] = __builtin_amdgcn_mfma_f32_16x16x32_bf16(afr[kk], cf[(n * 4 + kk) * 64 + l],
                                                                  accA[n], 0, 0, 0);
        #pragma unroll
        for (int n = 0; n < 4; ++n) {
            const int col = n * 16 + lr;
            const float cb = cbias[col];
            #pragma unroll
            for (int reg = 0; reg < 4; ++reg) {
                float sc = fast_tanh(accA[n][reg] + cb) * bf2f(kA[reg][n]) * bf2f(qA[reg][n]);
                macc[reg] += sc;
                int row = w * 16 + lg * 4 + reg;
                *reinterpret_cast<u16*>(
                    lds + row * 256 + ((col * 2) ^ ((row & 15) << 4))) = f2bf(sc);
            }
        }
    }

    // gather batch B (heads 4..7)
    u16x4 kB[4], qB[4];
    #pragma unroll
    for (int reg = 0; reg < 4; ++reg) {
        kB[reg] = *reinterpret_cast<const u16x4*>(&kbh[(size_t)si[reg] * 128 + lr * 8 + 4]);
        qB[reg] = *reinterpret_cast<const u16x4*>(&qbh[(size_t)di[reg] * 128 + lr * 8 + 4]);
    }

    // ---- half B: GEMM1 n=4..7 + epilogue ----
    {
        f32x4 accB[4];
        #pragma unroll
        for (int n = 0; n < 4; ++n) accB[n] = (f32x4){0.f, 0.f, 0.f, 0.f};
        #pragma unroll
        for (int n = 0; n < 4; ++n)
            #pragma unroll
            for (int kk = 0; kk < 4; ++kk)
                accB[n] = __builtin_amdgcn_mfma_f32_16x16x32_bf16(afr[kk], cf[((n + 4) * 4 + kk) * 64 + l],
                                                                  accB[n], 0, 0, 0);
        #pragma unroll
        for (int n = 0; n < 4; ++n) {
            const int col = (n + 4) * 16 + lr;
            const float cb = cbias[col];
            #pragma unroll
            for (int reg = 0; reg < 4; ++reg) {
                float sc = fast_tanh(accB[n][reg] + cb) * bf2f(kB[reg][n]) * bf2f(qB[reg][n]);
                macc[reg] += sc;
                int row = w * 16 + lg * 4 + reg;
                *reinterpret_cast<u16*>(
                    lds + row * 256 + ((col * 2) ^ ((row & 15) << 4))) = f2bf(sc);
            }
        }
    }
    #pragma unroll
    for (int reg = 0; reg < 4; ++reg) {
        int ei = base + w * 16 + lg * 4 + reg;
        if (vld[reg]) mean_out[(size_t)ei * 16 + lr] = macc[reg] * 0.125f;
    }

    // A-frags from score (in-wave LDS ordering)
    bf16x8 afr2[4];
    #pragma unroll
    for (int kk = 0; kk < 4; ++kk)
        afr2[kk] = *reinterpret_cast<const bf16x8*>(lds + rowbase + ((kk * 64 + lg * 16) ^ swz));

    // logit via indicator-MFMA: B[k][h] = (k>>4 == h); LINEAR store by edge id
    {
        bf16x8 ind[4];
        #pragma unroll
        for (int kk = 0; kk < 4; ++kk)
            #pragma unroll
            for (int j = 0; j < 8; ++j)
                ind[kk][j] = ((kk * 32 + lg * 8 + j) >> 4 == lr) ? (short)0x3F80 : (short)0;
        f32x4 lac = (f32x4){0.f, 0.f, 0.f, 0.f};
        #pragma unroll
        for (int kk = 0; kk < 4; ++kk)
            lac = __builtin_amdgcn_mfma_f32_16x16x32_bf16(afr2[kk], ind[kk], lac, 0, 0, 0);
        if (lr < 8) {
            #pragma unroll
            for (int reg = 0; reg < 4; ++reg) {
                int ei = base + w * 16 + lg * 4 + reg;
                if (vld[reg]) logit[(size_t)ei * 8 + lr] = lac[reg] * ATTN_SCALE;
            }
        }
    }

    // GEMM2 per-n: e_out = score @ eproj_w.T -> bf16 -> LDS (own rows)
    const bf16x8* ef = reinterpret_cast<const bf16x8*>(efrag);
    #pragma unroll
    for (int n = 0; n < 8; ++n) {
        f32x4 a2 = (f32x4){0.f, 0.f, 0.f, 0.f};
        #pragma unroll
        for (int kk = 0; kk < 4; ++kk)
            a2 = __builtin_amdgcn_mfma_f32_16x16x32_bf16(afr2[kk], ef[(n * 4 + kk) * 64 + l],
                                                         a2, 0, 0, 0);
        const int col = n * 16 + lr;
        const float eb = ebias[col];
        #pragma unroll
        for (int reg = 0; reg < 4; ++reg) {
            int row = w * 16 + lg * 4 + reg;
            *reinterpret_cast<u16*>(
                lds + row * 256 + ((col * 2) ^ ((row & 15) << 4))) = f2bf(a2[reg] + eb);
        }
    }
    // e_out coalesced stores from own rows
    #pragma unroll
    for (int rh = 0; rh < 2; ++rh) {
        #pragma unroll
        for (int ih = 0; ih < 2; ++ih) {
            int row = w * 16 + (l >> 3) + 8 * rh;
            int col = (l & 7) * 8 + 64 * ih;
            bf16x8 sv = *reinterpret_cast<const bf16x8*>(
                lds + row * 256 + ((col * 2) ^ ((row & 15) << 4)));
            float4 o0, o1;
            o0.x = bf2f((u16)sv[0]); o0.y = bf2f((u16)sv[1]);
            o0.z = bf2f((u16)sv[2]); o0.w = bf2f((u16)sv[3]);
            o1.x = bf2f((u16)sv[4]); o1.y = bf2f((u16)sv[5]);
            o1.z = bf2f((u16)sv[6]); o1.w = bf2f((u16)sv[7]);
            if (base + row < E) {
                *reinterpret_cast<float4*>(&e_out[(size_t)(base + row) * 128 + col]) = o0;
                *reinterpret_cast<float4*>(&e_out[(size_t)(base + row) * 128 + col + 4]) = o1;
            }
        }
    }
}

// ---------- per-node softmax + aggregation ----------

__global__ __launch_bounds__(256) void node_kernel(
    const int* __restrict__ offsets, const int* __restrict__ eidx,
    const int* __restrict__ src, const float* __restrict__ logit,
    const u16* __restrict__ vbh, float* __restrict__ hagg, int N)
{
    __shared__ int   ls_src[4][64];
    __shared__ float ls_l[4][64][8];
    const int t = threadIdx.x, w = t >> 6, lane = t & 63;
    const int node = blockIdx.x * 4 + w;
    int off = 0, deg = 0;
    if (node < N) { off = offsets[node]; deg = offsets[node + 1] - off; }

    const int h = lane & 7, g = lane >> 3;
    float m = -3.0e38f, s = 0.f;

    for (int c0 = 0; c0 < deg; c0 += 64) {
        int cnt = min(64, deg - c0);
        if (lane < cnt) {
            int eid = eidx[off + c0 + lane];
            ls_src[w][lane] = src[eid];
            float4 l0 = *reinterpret_cast<const float4*>(&logit[(size_t)eid * 8]);
            float4 l1 = *reinterpret_cast<const float4*>(&logit[(size_t)eid * 8 + 4]);
            *reinterpret_cast<float4*>(&ls_l[w][lane][0]) = l0;
            *reinterpret_cast<float4*>(&ls_l[w][lane][4]) = l1;
        }
        __asm__ __volatile__("s_waitcnt lgkmcnt(0)" ::: "memory");
        float cm = -3.0e38f;
        for (int j = g; j < cnt; j += 8) cm = fmaxf(cm, ls_l[w][j][h]);
        cm = fmaxf(cm, __shfl_xor(cm, 8));
        cm = fmaxf(cm, __shfl_xor(cm, 16));
        cm = fmaxf(cm, __shfl_xor(cm, 32));
        float mn = fmaxf(m, cm);
        float cs = 0.f;
        for (int j = g; j < cnt; j += 8) cs += __expf(ls_l[w][j][h] - mn);
        cs += __shfl_xor(cs, 8); cs += __shfl_xor(cs, 16); cs += __shfl_xor(cs, 32);
        s = s * __expf(m - mn) + cs;
        m = mn;
    }
    float inv = (deg > 0) ? 1.f / s : 0.f;

    float a0 = 0.f, a1 = 0.f;
    const int d0 = lane, d1 = lane + 64, h0 = lane >> 4, h1 = 4 + h0;
    for (int c0 = 0; c0 < deg; c0 += 64) {
        int cnt = min(64, deg - c0);
        if (deg > 64 && lane < cnt) {
            int eid = eidx[off + c0 + lane];
            ls_src[w][lane] = src[eid];
            float4 l0 = *reinterpret_cast<const float4*>(&logit[(size_t)eid * 8]);
            float4 l1 = *reinterpret_cast<const float4*>(&logit[(size_t)eid * 8 + 4]);
            *reinterpret_cast<float4*>(&ls_l[w][lane][0]) = l0;
            *reinterpret_cast<float4*>(&ls_l[w][lane][4]) = l1;
        }
        __asm__ __volatile__("s_waitcnt lgkmcnt(0)" ::: "memory");
        for (int j = g; j < cnt; j += 8)
            ls_l[w][j][h] = __expf(ls_l[w][j][h] - m) * inv;
        __asm__ __volatile__("s_waitcnt lgkmcnt(0)" ::: "memory");
        #pragma unroll 4
        for (int j = 0; j < cnt; ++j) {
            int sn = ls_src[w][j];
            float w0 = ls_l[w][j][h0], w1 = ls_l[w][j][h1];
            a0 += w0 * bf2f(vbh[(size_t)sn * 128 + d0]);
            a1 += w1 * bf2f(vbh[(size_t)sn * 128 + d1]);
        }
    }
    if (node < N) {
        hagg[(size_t)node * 128 + d0] = a0;
        hagg[(size_t)node * 128 + d1] = a1;
    }
}

// ---------- launcher ----------

extern "C" void kernel_launch(void* const* d_in, const int* in_sizes, int n_in,
                              void* d_out, int out_size, void* d_ws, size_t ws_size,
                              hipStream_t stream)
{
    const float* h       = (const float*)d_in[0];
    const float* e       = (const float*)d_in[1];
    const int*   src     = (const int*)d_in[2];
    const int*   dst     = (const int*)d_in[3];
    const float* qkv_w   = (const float*)d_in[4];
    const float* qkv_b   = (const float*)d_in[5];
    const float* c_w     = (const float*)d_in[6];
    const float* c_b     = (const float*)d_in[7];
    const float* hproj_w = (const float*)d_in[8];
    const float* hproj_b = (const float*)d_in[9];
    const float* eproj_w = (const float*)d_in[10];
    const float* eproj_b = (const float*)d_in[11];

    const int N = in_sizes[0] / 128;
    const int E = in_sizes[1] / 128;

    float* h_out    = (float*)d_out;
    float* e_out    = h_out + (size_t)N * 128;
    float* mean_out = e_out + (size_t)E * 128;

    char* wp = (char*)d_ws;
    auto alloc = [&](size_t b) {
        void* p = (void*)wp;
        wp += (b + 255) & ~(size_t)255;
        return p;
    };
    short* qkvfrag = (short*)alloc(sizeof(short) * 3 * 2048 * 8);
    short* cfragb  = (short*)alloc(sizeof(short) * 2048 * 8);
    short* efragb  = (short*)alloc(sizeof(short) * 2048 * 8);
    short* hpfrag  = (short*)alloc(sizeof(short) * 2048 * 8);
    u16*   qbh     = (u16*)alloc(sizeof(u16) * (size_t)N * 128);
    u16*   kbh     = (u16*)alloc(sizeof(u16) * (size_t)N * 128);
    u16*   vbh     = (u16*)alloc(sizeof(u16) * (size_t)N * 128);
    float* hagg    = (float*)alloc(sizeof(float) * (size_t)N * 128);
    float* logit   = (float*)alloc(sizeof(float) * (size_t)E * 8);
    int*   counts  = (int*)alloc(sizeof(int) * (N + 1));
    int*   offs    = (int*)alloc(sizeof(int) * (N + 1));
    int*   cursor  = (int*)alloc(sizeof(int) * (N + 1));
    int*   stmp    = (int*)alloc(sizeof(int) * (N + 1));
    int*   bsum    = (int*)alloc(sizeof(int) * 64);
    int*   eidx    = (int*)alloc(sizeof(int) * E);

    hipMemsetAsync(counts, 0, sizeof(int) * (N + 1), stream);

    make_frag<<<8, 256, 0, stream>>>(qkv_w, qkvfrag);
    make_frag<<<8, 256, 0, stream>>>(qkv_w + 128 * 128, qkvfrag + 2048 * 8);
    make_frag<<<8, 256, 0, stream>>>(qkv_w + 2 * 128 * 128, qkvfrag + 2 * 2048 * 8);
    make_frag<<<8, 256, 0, stream>>>(c_w, cfragb);
    make_frag<<<8, 256, 0, stream>>>(eproj_w, efragb);
    make_frag<<<8, 256, 0, stream>>>(hproj_w, hpfrag);

    qkv_gemm<<<(N + 63) / 64, 256, 0, stream>>>(h, qkvfrag, qkv_b, qbh, kbh, vbh, N);

    hist_kernel<<<(E + 255) / 256, 256, 0, stream>>>(dst, counts, E);
    int nb = (N + 1023) / 1024;
    scan1<<<nb, 256, 0, stream>>>(counts, stmp, bsum, N);
    scan2<<<1, 64, 0, stream>>>(bsum, nb);
    scan3<<<(N + 255) / 256, 256, 0, stream>>>(stmp, bsum, offs, N);
    copy_kernel<<<(N + 256) / 256, 256, 0, stream>>>(offs, cursor, N + 1);
    scatter_kernel<<<(E + 255) / 256, 256, 0, stream>>>(dst, cursor, eidx, E);

    edge_mfma<<<(E + 63) / 64, 256, 0, stream>>>(e, src, dst, cfragb, c_b, efragb,
                                                 eproj_b, qbh, kbh, e_out, mean_out, logit, E);

    node_kernel<<<(N + 3) / 4, 256, 0, stream>>>(offs, eidx, src, logit, vbh, hagg, N);

    gemm128<<<(N + 63) / 64, 256, 0, stream>>>(hagg, hpfrag, hproj_b, h_out, N);
}

// Round 10
// 407.421 us; speedup vs baseline: 1.6064x; 1.1793x over previous
//
#include <hip/hip_runtime.h>
#include <cmath>

typedef __attribute__((ext_vector_type(8))) short bf16x8;
typedef __attribute__((ext_vector_type(4))) float f32x4;
typedef __attribute__((ext_vector_type(4))) unsigned short u16x4;
typedef __attribute__((ext_vector_type(8))) unsigned short u16x8;
typedef unsigned short u16;

#define ATTN_SCALE 0.25f

__device__ inline u16 f2bf(float x) {
    union { float f; unsigned u; } v; v.f = x;
    unsigned r = v.u + 0x7FFFu + ((v.u >> 16) & 1u);
    return (u16)(r >> 16);
}
__device__ inline float bf2f(u16 u) {
    union { unsigned u; float f; } v; v.u = ((unsigned)u) << 16; return v.f;
}
__device__ inline float fast_tanh(float x) {
    float xc = fminf(fmaxf(x, -15.f), 15.f);
    float t = __expf(2.f * xc);
    return (t - 1.f) * __builtin_amdgcn_rcpf(t + 1.f);
}

// ---------- CSR build ----------

__global__ __launch_bounds__(256) void hist_kernel(const int* __restrict__ dst,
                                                   int* __restrict__ counts, int E) {
    int i = blockIdx.x * 256 + threadIdx.x;
    if (i < E) atomicAdd(&counts[dst[i]], 1);
}

__global__ __launch_bounds__(256) void scan1(const int* __restrict__ counts,
                                             int* __restrict__ tmp, int* __restrict__ bsum, int N) {
    __shared__ int wsum[4];
    int b = blockIdx.x, t = threadIdx.x;
    int base = b * 1024 + t * 4;
    int v0 = (base + 0 < N) ? counts[base + 0] : 0;
    int v1 = (base + 1 < N) ? counts[base + 1] : 0;
    int v2 = (base + 2 < N) ? counts[base + 2] : 0;
    int v3 = (base + 3 < N) ? counts[base + 3] : 0;
    int p0 = v0, p1 = p0 + v1, p2 = p1 + v2, p3 = p2 + v3;
    int s = p3;
    int lane = t & 63, wid = t >> 6;
    int sc = s;
    #pragma unroll
    for (int d = 1; d < 64; d <<= 1) {
        int o = __shfl_up(sc, d);
        if (lane >= d) sc += o;
    }
    if (lane == 63) wsum[wid] = sc;
    __syncthreads();
    int wof = 0;
    #pragma unroll
    for (int i = 0; i < 4; ++i) if (i < wid) wof += wsum[i];
    int excl = wof + sc - s;
    if (base + 0 < N) tmp[base + 0] = excl + p0;
    if (base + 1 < N) tmp[base + 1] = excl + p1;
    if (base + 2 < N) tmp[base + 2] = excl + p2;
    if (base + 3 < N) tmp[base + 3] = excl + p3;
    if (t == 255) bsum[b] = wof + sc;
}

__global__ void scan2(int* __restrict__ bsum, int nb) {
    int t = threadIdx.x;
    int v = (t < nb) ? bsum[t] : 0;
    int sc = v;
    #pragma unroll
    for (int d = 1; d < 64; d <<= 1) {
        int o = __shfl_up(sc, d);
        if (t >= d) sc += o;
    }
    if (t < nb) bsum[t] = sc - v;
}

__global__ __launch_bounds__(256) void scan3(const int* __restrict__ tmp,
                                             const int* __restrict__ bsum,
                                             int* __restrict__ offsets, int N) {
    int i = blockIdx.x * 256 + threadIdx.x;
    if (i < N) offsets[i + 1] = tmp[i] + bsum[i >> 10];
    if (i == 0) offsets[0] = 0;
}

__global__ __launch_bounds__(256) void copy_kernel(const int* __restrict__ a,
                                                   int* __restrict__ b, int n) {
    int i = blockIdx.x * 256 + threadIdx.x;
    if (i < n) b[i] = a[i];
}

__global__ __launch_bounds__(256) void scatter_kernel(const int* __restrict__ dst,
                                                      int* __restrict__ cursor,
                                                      int* __restrict__ eidx, int E) {
    int i = blockIdx.x * 256 + threadIdx.x;
    if (i < E) {
        int p = atomicAdd(&cursor[dst[i]], 1);
        eidx[p] = i;
    }
}

// ---------- weight -> MFMA B-fragment (bf16, frag-linear) ----------
__global__ __launch_bounds__(256) void make_frag(const float* __restrict__ W,
                                                 short* __restrict__ out) {
    int id = blockIdx.x * 256 + threadIdx.x;
    if (id >= 2048) return;
    int l = id & 63, t16 = id >> 6;
    int kk = t16 & 3, n = t16 >> 2;
    int col = n * 16 + (l & 15);
    int k0 = kk * 32 + (l >> 4) * 8;
    #pragma unroll
    for (int j = 0; j < 8; ++j)
        out[id * 8 + j] = (short)f2bf(W[col * 128 + k0 + j]);
}

// ---------- qkv GEMM: q,k -> dim-major packed bf16 [node][d16][head]; v standard ----------

__global__ __launch_bounds__(256) void qkv_gemm(
    const float* __restrict__ X, const short* __restrict__ frag,
    const float* __restrict__ bias,
    u16* __restrict__ Yq, u16* __restrict__ Yk, u16* __restrict__ Yv, int R)
{
    __shared__ __align__(16) char lds[64 * 256];
    const int t = threadIdx.x;
    const int base = blockIdx.x * 64;
    for (int i = 0; i < 8; ++i) {
        int flat = i * 1024 + t * 4;
        int r = flat >> 7, k = flat & 127;
        float4 v = make_float4(0.f, 0.f, 0.f, 0.f);
        if (base + r < R) v = *reinterpret_cast<const float4*>(&X[(size_t)(base + r) * 128 + k]);
        ushort4 b;
        b.x = f2bf(v.x); b.y = f2bf(v.y); b.z = f2bf(v.z); b.w = f2bf(v.w);
        *reinterpret_cast<ushort4*>(lds + r * 256 + ((k * 2) ^ ((r & 15) << 4))) = b;
    }
    __syncthreads();
    const int w = t >> 6, l = t & 63, lr = l & 15, lg = l >> 4;
    const int rowbase = (w * 16 + lr) * 256, swz = lr << 4;
    bf16x8 afr[4];
    #pragma unroll
    for (int kk = 0; kk < 4; ++kk)
        afr[kk] = *reinterpret_cast<const bf16x8*>(lds + rowbase + ((kk * 64 + lg * 16) ^ swz));
    for (int ch = 0; ch < 3; ++ch) {
        const bf16x8* bf = reinterpret_cast<const bf16x8*>(frag + ch * 2048 * 8);
        f32x4 acc[8];
        #pragma unroll
        for (int n = 0; n < 8; ++n) acc[n] = (f32x4){0.f, 0.f, 0.f, 0.f};
        #pragma unroll
        for (int n = 0; n < 8; ++n)
            #pragma unroll
            for (int kk = 0; kk < 4; ++kk)
                acc[n] = __builtin_amdgcn_mfma_f32_16x16x32_bf16(afr[kk], bf[(n * 4 + kk) * 64 + l],
                                                                 acc[n], 0, 0, 0);
        if (ch < 2) {
            u16* Y = (ch == 0) ? Yq : Yk;
            float bv[8];
            #pragma unroll
            for (int n = 0; n < 8; ++n) bv[n] = bias[ch * 128 + n * 16 + lr];
            #pragma unroll
            for (int reg = 0; reg < 4; ++reg) {
                int r = base + w * 16 + lg * 4 + reg;
                if (r < R) {
                    u16x8 pk;
                    #pragma unroll
                    for (int n = 0; n < 8; ++n) pk[n] = f2bf(acc[n][reg] + bv[n]);
                    *reinterpret_cast<u16x8*>(&Y[(size_t)r * 128 + lr * 8]) = pk;
                }
            }
        } else {
            #pragma unroll
            for (int n = 0; n < 8; ++n) {
                int col = n * 16 + lr;
                float bv = bias[ch * 128 + col];
                #pragma unroll
                for (int reg = 0; reg < 4; ++reg) {
                    int r = base + w * 16 + lg * 4 + reg;
                    if (r < R) Yv[(size_t)r * 128 + col] = f2bf(acc[n][reg] + bv);
                }
            }
        }
    }
}

// ---------- generic rows x 128 @ 128x128 MFMA GEMM, f32 out (hproj) ----------

__global__ __launch_bounds__(256) void gemm128(
    const float* __restrict__ X, const short* __restrict__ frag,
    const float* __restrict__ bias, float* __restrict__ Y, int R)
{
    __shared__ __align__(16) char lds[64 * 256];
    const int t = threadIdx.x;
    const int base = blockIdx.x * 64;
    for (int i = 0; i < 8; ++i) {
        int flat = i * 1024 + t * 4;
        int r = flat >> 7, k = flat & 127;
        float4 v = make_float4(0.f, 0.f, 0.f, 0.f);
        if (base + r < R) v = *reinterpret_cast<const float4*>(&X[(size_t)(base + r) * 128 + k]);
        ushort4 b;
        b.x = f2bf(v.x); b.y = f2bf(v.y); b.z = f2bf(v.z); b.w = f2bf(v.w);
        *reinterpret_cast<ushort4*>(lds + r * 256 + ((k * 2) ^ ((r & 15) << 4))) = b;
    }
    __syncthreads();
    const int w = t >> 6, l = t & 63, lr = l & 15, lg = l >> 4;
    const int rowbase = (w * 16 + lr) * 256, swz = lr << 4;
    bf16x8 afr[4];
    #pragma unroll
    for (int kk = 0; kk < 4; ++kk)
        afr[kk] = *reinterpret_cast<const bf16x8*>(lds + rowbase + ((kk * 64 + lg * 16) ^ swz));
    const bf16x8* bf = reinterpret_cast<const bf16x8*>(frag);
    f32x4 acc[8];
    #pragma unroll
    for (int n = 0; n < 8; ++n) acc[n] = (f32x4){0.f, 0.f, 0.f, 0.f};
    #pragma unroll
    for (int n = 0; n < 8; ++n)
        #pragma unroll
        for (int kk = 0; kk < 4; ++kk)
            acc[n] = __builtin_amdgcn_mfma_f32_16x16x32_bf16(afr[kk], bf[(n * 4 + kk) * 64 + l],
                                                             acc[n], 0, 0, 0);
    #pragma unroll
    for (int n = 0; n < 8; ++n) {
        int col = n * 16 + lr;
        float bv = bias[col];
        #pragma unroll
        for (int reg = 0; reg < 4; ++reg) {
            int r = base + w * 16 + lg * 4 + reg;
            if (r < R) Y[(size_t)r * 128 + col] = acc[n][reg] + bv;
        }
    }
}

// ---------- fused edge kernel: BARRIER-FREE ----------
// Wave w only touches rows w*16..w*16+15. GEMM1 A-frags load straight from
// global e (row base+w*16+lr, k contiguous) with in-register f2bf; LDS holds
// only the wave-private swizzled score tile (written+read by same wave,
// in-wave ds ordering). Zero __syncthreads -> waves are independent streams.

__global__ __launch_bounds__(256) void edge_mfma(
    const float* __restrict__ e, const int* __restrict__ src, const int* __restrict__ dst,
    const short* __restrict__ cfrag, const float* __restrict__ cbias,
    const short* __restrict__ efrag, const float* __restrict__ ebias,
    const u16* __restrict__ qbh, const u16* __restrict__ kbh,
    float* __restrict__ e_out, float* __restrict__ mean_out,
    float* __restrict__ logit, int E)
{
    __shared__ __align__(16) char lds[64 * 256];
    const int t = threadIdx.x;
    const int base = blockIdx.x * 64;
    const int w = t >> 6, l = t & 63;
    const int lr = l & 15, lg = l >> 4;
    const int rowbase = (w * 16 + lr) * 256;
    const int swz = lr << 4;

    int si[4], di[4];
    bool vld[4];
    #pragma unroll
    for (int reg = 0; reg < 4; ++reg) {
        int ei = base + w * 16 + lg * 4 + reg;
        vld[reg] = ei < E;
        int ce = vld[reg] ? ei : (E - 1);
        si[reg] = src[ce];
        di[reg] = dst[ce];
    }
    // gather batch A (heads 0..3): one 8B load per reg per operand
    u16x4 kA[4], qA[4];
    #pragma unroll
    for (int reg = 0; reg < 4; ++reg) {
        kA[reg] = *reinterpret_cast<const u16x4*>(&kbh[(size_t)si[reg] * 128 + lr * 8]);
        qA[reg] = *reinterpret_cast<const u16x4*>(&qbh[(size_t)di[reg] * 128 + lr * 8]);
    }

    // GEMM1 A-fragments straight from global e (own row), f2bf in-register
    const int myrow = base + w * 16 + lr;
    const float* erow = e + (size_t)(myrow < E ? myrow : (E - 1)) * 128;
    bf16x8 afr[4];
    #pragma unroll
    for (int kk = 0; kk < 4; ++kk) {
        float4 f0 = *reinterpret_cast<const float4*>(erow + kk * 32 + lg * 8);
        float4 f1 = *reinterpret_cast<const float4*>(erow + kk * 32 + lg * 8 + 4);
        bf16x8 a;
        a[0] = (short)f2bf(f0.x); a[1] = (short)f2bf(f0.y);
        a[2] = (short)f2bf(f0.z); a[3] = (short)f2bf(f0.w);
        a[4] = (short)f2bf(f1.x); a[5] = (short)f2bf(f1.y);
        a[6] = (short)f2bf(f1.z); a[7] = (short)f2bf(f1.w);
        afr[kk] = a;
    }

    const bf16x8* cf = reinterpret_cast<const bf16x8*>(cfrag);
    float macc[4] = {0.f, 0.f, 0.f, 0.f};

    // ---- half A: GEMM1 n=0..3 + epilogue ----
    {
        f32x4 accA[4];
        #pragma unroll
        for (int n = 0; n < 4; ++n) accA[n] = (f32x4){0.f, 0.f, 0.f, 0.f};
        #pragma unroll
        for (int n = 0; n < 4; ++n)
            #pragma unroll
            for (int kk = 0; kk < 4; ++kk)
                accA[n] = __builtin_amdgcn_mfma_f32_16x16x32_bf16(afr[kk], cf[(n * 4 + kk) * 64 + l],
                                                                  accA[n], 0, 0, 0);
        #pragma unroll
        for (int n = 0; n < 4; ++n) {
            const int col = n * 16 + lr;
            const float cb = cbias[col];
            #pragma unroll
            for (int reg = 0; reg < 4; ++reg) {
                float sc = fast_tanh(accA[n][reg] + cb) * bf2f(kA[reg][n]) * bf2f(qA[reg][n]);
                macc[reg] += sc;
                int row = w * 16 + lg * 4 + reg;
                *reinterpret_cast<u16*>(
                    lds + row * 256 + ((col * 2) ^ ((row & 15) << 4))) = f2bf(sc);
            }
        }
    }

    // gather batch B (heads 4..7)
    u16x4 kB[4], qB[4];
    #pragma unroll
    for (int reg = 0; reg < 4; ++reg) {
        kB[reg] = *reinterpret_cast<const u16x4*>(&kbh[(size_t)si[reg] * 128 + lr * 8 + 4]);
        qB[reg] = *reinterpret_cast<const u16x4*>(&qbh[(size_t)di[reg] * 128 + lr * 8 + 4]);
    }

    // ---- half B: GEMM1 n=4..7 + epilogue ----
    {
        f32x4 accB[4];
        #pragma unroll
        for (int n = 0; n < 4; ++n) accB[n] = (f32x4){0.f, 0.f, 0.f, 0.f};
        #pragma unroll
        for (int n = 0; n < 4; ++n)
            #pragma unroll
            for (int kk = 0; kk < 4; ++kk)
                accB[n] = __builtin_amdgcn_mfma_f32_16x16x32_bf16(afr[kk], cf[((n + 4) * 4 + kk) * 64 + l],
                                                                  accB[n], 0, 0, 0);
        #pragma unroll
        for (int n = 0; n < 4; ++n) {
            const int col = (n + 4) * 16 + lr;
            const float cb = cbias[col];
            #pragma unroll
            for (int reg = 0; reg < 4; ++reg) {
                float sc = fast_tanh(accB[n][reg] + cb) * bf2f(kB[reg][n]) * bf2f(qB[reg][n]);
                macc[reg] += sc;
                int row = w * 16 + lg * 4 + reg;
                *reinterpret_cast<u16*>(
                    lds + row * 256 + ((col * 2) ^ ((row & 15) << 4))) = f2bf(sc);
            }
        }
    }
    #pragma unroll
    for (int reg = 0; reg < 4; ++reg) {
        int ei = base + w * 16 + lg * 4 + reg;
        if (vld[reg]) mean_out[(size_t)ei * 16 + lr] = macc[reg] * 0.125f;
    }

    // A-frags from score (same wave wrote these rows; in-wave ds ordering)
    bf16x8 afr2[4];
    #pragma unroll
    for (int kk = 0; kk < 4; ++kk)
        afr2[kk] = *reinterpret_cast<const bf16x8*>(lds + rowbase + ((kk * 64 + lg * 16) ^ swz));

    // logit via indicator-MFMA: B[k][h] = (k>>4 == h); LINEAR store by edge id
    {
        bf16x8 ind[4];
        #pragma unroll
        for (int kk = 0; kk < 4; ++kk)
            #pragma unroll
            for (int j = 0; j < 8; ++j)
                ind[kk][j] = ((kk * 32 + lg * 8 + j) >> 4 == lr) ? (short)0x3F80 : (short)0;
        f32x4 lac = (f32x4){0.f, 0.f, 0.f, 0.f};
        #pragma unroll
        for (int kk = 0; kk < 4; ++kk)
            lac = __builtin_amdgcn_mfma_f32_16x16x32_bf16(afr2[kk], ind[kk], lac, 0, 0, 0);
        if (lr < 8) {
            #pragma unroll
            for (int reg = 0; reg < 4; ++reg) {
                int ei = base + w * 16 + lg * 4 + reg;
                if (vld[reg]) logit[(size_t)ei * 8 + lr] = lac[reg] * ATTN_SCALE;
            }
        }
    }

    // GEMM2 per-n: e_out = score @ eproj_w.T -> bf16 -> LDS (own rows)
    const bf16x8* ef = reinterpret_cast<const bf16x8*>(efrag);
    #pragma unroll
    for (int n = 0; n < 8; ++n) {
        f32x4 a2 = (f32x4){0.f, 0.f, 0.f, 0.f};
        #pragma unroll
        for (int kk = 0; kk < 4; ++kk)
            a2 = __builtin_amdgcn_mfma_f32_16x16x32_bf16(afr2[kk], ef[(n * 4 + kk) * 64 + l],
                                                         a2, 0, 0, 0);
        const int col = n * 16 + lr;
        const float eb = ebias[col];
        #pragma unroll
        for (int reg = 0; reg < 4; ++reg) {
            int row = w * 16 + lg * 4 + reg;
            *reinterpret_cast<u16*>(
                lds + row * 256 + ((col * 2) ^ ((row & 15) << 4))) = f2bf(a2[reg] + eb);
        }
    }
    // e_out coalesced stores from own rows (wave-private rows)
    #pragma unroll
    for (int rh = 0; rh < 2; ++rh) {
        #pragma unroll
        for (int ih = 0; ih < 2; ++ih) {
            int row = w * 16 + (l >> 3) + 8 * rh;
            int col = (l & 7) * 8 + 64 * ih;
            bf16x8 sv = *reinterpret_cast<const bf16x8*>(
                lds + row * 256 + ((col * 2) ^ ((row & 15) << 4)));
            float4 o0, o1;
            o0.x = bf2f((u16)sv[0]); o0.y = bf2f((u16)sv[1]);
            o0.z = bf2f((u16)sv[2]); o0.w = bf2f((u16)sv[3]);
            o1.x = bf2f((u16)sv[4]); o1.y = bf2f((u16)sv[5]);
            o1.z = bf2f((u16)sv[6]); o1.w = bf2f((u16)sv[7]);
            if (base + row < E) {
                *reinterpret_cast<float4*>(&e_out[(size_t)(base + row) * 128 + col]) = o0;
                *reinterpret_cast<float4*>(&e_out[(size_t)(base + row) * 128 + col + 4]) = o1;
            }
        }
    }
}

// ---------- per-node softmax + aggregation ----------

__global__ __launch_bounds__(256) void node_kernel(
    const int* __restrict__ offsets, const int* __restrict__ eidx,
    const int* __restrict__ src, const float* __restrict__ logit,
    const u16* __restrict__ vbh, float* __restrict__ hagg, int N)
{
    __shared__ int   ls_src[4][64];
    __shared__ float ls_l[4][64][8];
    const int t = threadIdx.x, w = t >> 6, lane = t & 63;
    const int node = blockIdx.x * 4 + w;
    int off = 0, deg = 0;
    if (node < N) { off = offsets[node]; deg = offsets[node + 1] - off; }

    const int h = lane & 7, g = lane >> 3;
    float m = -3.0e38f, s = 0.f;

    for (int c0 = 0; c0 < deg; c0 += 64) {
        int cnt = min(64, deg - c0);
        if (lane < cnt) {
            int eid = eidx[off + c0 + lane];
            ls_src[w][lane] = src[eid];
            float4 l0 = *reinterpret_cast<const float4*>(&logit[(size_t)eid * 8]);
            float4 l1 = *reinterpret_cast<const float4*>(&logit[(size_t)eid * 8 + 4]);
            *reinterpret_cast<float4*>(&ls_l[w][lane][0]) = l0;
            *reinterpret_cast<float4*>(&ls_l[w][lane][4]) = l1;
        }
        __asm__ __volatile__("s_waitcnt lgkmcnt(0)" ::: "memory");
        float cm = -3.0e38f;
        for (int j = g; j < cnt; j += 8) cm = fmaxf(cm, ls_l[w][j][h]);
        cm = fmaxf(cm, __shfl_xor(cm, 8));
        cm = fmaxf(cm, __shfl_xor(cm, 16));
        cm = fmaxf(cm, __shfl_xor(cm, 32));
        float mn = fmaxf(m, cm);
        float cs = 0.f;
        for (int j = g; j < cnt; j += 8) cs += __expf(ls_l[w][j][h] - mn);
        cs += __shfl_xor(cs, 8); cs += __shfl_xor(cs, 16); cs += __shfl_xor(cs, 32);
        s = s * __expf(m - mn) + cs;
        m = mn;
    }
    float inv = (deg > 0) ? 1.f / s : 0.f;

    float a0 = 0.f, a1 = 0.f;
    const int d0 = lane, d1 = lane + 64, h0 = lane >> 4, h1 = 4 + h0;
    for (int c0 = 0; c0 < deg; c0 += 64) {
        int cnt = min(64, deg - c0);
        if (deg > 64 && lane < cnt) {
            int eid = eidx[off + c0 + lane];
            ls_src[w][lane] = src[eid];
            float4 l0 = *reinterpret_cast<const float4*>(&logit[(size_t)eid * 8]);
            float4 l1 = *reinterpret_cast<const float4*>(&logit[(size_t)eid * 8 + 4]);
            *reinterpret_cast<float4*>(&ls_l[w][lane][0]) = l0;
            *reinterpret_cast<float4*>(&ls_l[w][lane][4]) = l1;
        }
        __asm__ __volatile__("s_waitcnt lgkmcnt(0)" ::: "memory");
        for (int j = g; j < cnt; j += 8)
            ls_l[w][j][h] = __expf(ls_l[w][j][h] - m) * inv;
        __asm__ __volatile__("s_waitcnt lgkmcnt(0)" ::: "memory");
        #pragma unroll 4
        for (int j = 0; j < cnt; ++j) {
            int sn = ls_src[w][j];
            float w0 = ls_l[w][j][h0], w1 = ls_l[w][j][h1];
            a0 += w0 * bf2f(vbh[(size_t)sn * 128 + d0]);
            a1 += w1 * bf2f(vbh[(size_t)sn * 128 + d1]);
        }
    }
    if (node < N) {
        hagg[(size_t)node * 128 + d0] = a0;
        hagg[(size_t)node * 128 + d1] = a1;
    }
}

// ---------- launcher ----------

extern "C" void kernel_launch(void* const* d_in, const int* in_sizes, int n_in,
                              void* d_out, int out_size, void* d_ws, size_t ws_size,
                              hipStream_t stream)
{
    const float* h       = (const float*)d_in[0];
    const float* e       = (const float*)d_in[1];
    const int*   src     = (const int*)d_in[2];
    const int*   dst     = (const int*)d_in[3];
    const float* qkv_w   = (const float*)d_in[4];
    const float* qkv_b   = (const float*)d_in[5];
    const float* c_w     = (const float*)d_in[6];
    const float* c_b     = (const float*)d_in[7];
    const float* hproj_w = (const float*)d_in[8];
    const float* hproj_b = (const float*)d_in[9];
    const float* eproj_w = (const float*)d_in[10];
    const float* eproj_b = (const float*)d_in[11];

    const int N = in_sizes[0] / 128;
    const int E = in_sizes[1] / 128;

    float* h_out    = (float*)d_out;
    float* e_out    = h_out + (size_t)N * 128;
    float* mean_out = e_out + (size_t)E * 128;

    char* wp = (char*)d_ws;
    auto alloc = [&](size_t b) {
        void* p = (void*)wp;
        wp += (b + 255) & ~(size_t)255;
        return p;
    };
    short* qkvfrag = (short*)alloc(sizeof(short) * 3 * 2048 * 8);
    short* cfragb  = (short*)alloc(sizeof(short) * 2048 * 8);
    short* efragb  = (short*)alloc(sizeof(short) * 2048 * 8);
    short* hpfrag  = (short*)alloc(sizeof(short) * 2048 * 8);
    u16*   qbh     = (u16*)alloc(sizeof(u16) * (size_t)N * 128);
    u16*   kbh     = (u16*)alloc(sizeof(u16) * (size_t)N * 128);
    u16*   vbh     = (u16*)alloc(sizeof(u16) * (size_t)N * 128);
    float* hagg    = (float*)alloc(sizeof(float) * (size_t)N * 128);
    float* logit   = (float*)alloc(sizeof(float) * (size_t)E * 8);
    int*   counts  = (int*)alloc(sizeof(int) * (N + 1));
    int*   offs    = (int*)alloc(sizeof(int) * (N + 1));
    int*   cursor  = (int*)alloc(sizeof(int) * (N + 1));
    int*   stmp    = (int*)alloc(sizeof(int) * (N + 1));
    int*   bsum    = (int*)alloc(sizeof(int) * 64);
    int*   eidx    = (int*)alloc(sizeof(int) * E);

    hipMemsetAsync(counts, 0, sizeof(int) * (N + 1), stream);

    make_frag<<<8, 256, 0, stream>>>(qkv_w, qkvfrag);
    make_frag<<<8, 256, 0, stream>>>(qkv_w + 128 * 128, qkvfrag + 2048 * 8);
    make_frag<<<8, 256, 0, stream>>>(qkv_w + 2 * 128 * 128, qkvfrag + 2 * 2048 * 8);
    make_frag<<<8, 256, 0, stream>>>(c_w, cfragb);
    make_frag<<<8, 256, 0, stream>>>(eproj_w, efragb);
    make_frag<<<8, 256, 0, stream>>>(hproj_w, hpfrag);

    qkv_gemm<<<(N + 63) / 64, 256, 0, stream>>>(h, qkvfrag, qkv_b, qbh, kbh, vbh, N);

    hist_kernel<<<(E + 255) / 256, 256, 0, stream>>>(dst, counts, E);
    int nb = (N + 1023) / 1024;
    scan1<<<nb, 256, 0, stream>>>(counts, stmp, bsum, N);
    scan2<<<1, 64, 0, stream>>>(bsum, nb);
    scan3<<<(N + 255) / 256, 256, 0, stream>>>(stmp, bsum, offs, N);
    copy_kernel<<<(N + 256) / 256, 256, 0, stream>>>(offs, cursor, N + 1);
    scatter_kernel<<<(E + 255) / 256, 256, 0, stream>>>(dst, cursor, eidx, E);

    edge_mfma<<<(E + 63) / 64, 256, 0, stream>>>(e, src, dst, cfragb, c_b, efragb,
                                                 eproj_b, qbh, kbh, e_out, mean_out, logit, E);

    node_kernel<<<(N + 3) / 4, 256, 0, stream>>>(offs, eidx, src, logit, vbh, hagg, N);

    gemm128<<<(N + 63) / 64, 256, 0, stream>>>(hagg, hpfrag, hproj_b, h_out, N);
}

// Round 11
// 400.396 us; speedup vs baseline: 1.6346x; 1.0175x over previous
//
#include <hip/hip_runtime.h>
#include <cmath>

typedef __attribute__((ext_vector_type(8))) short bf16x8;
typedef __attribute__((ext_vector_type(4))) float f32x4;
typedef __attribute__((ext_vector_type(4))) unsigned short u16x4;
typedef __attribute__((ext_vector_type(8))) unsigned short u16x8;
typedef unsigned short u16;

#define ATTN_SCALE 0.25f

__device__ inline u16 f2bf(float x) {
    union { float f; unsigned u; } v; v.f = x;
    unsigned r = v.u + 0x7FFFu + ((v.u >> 16) & 1u);
    return (u16)(r >> 16);
}
__device__ inline float bf2f(u16 u) {
    union { unsigned u; float f; } v; v.u = ((unsigned)u) << 16; return v.f;
}
__device__ inline float fast_tanh(float x) {
    float xc = fminf(fmaxf(x, -15.f), 15.f);
    float t = __expf(2.f * xc);
    return (t - 1.f) * __builtin_amdgcn_rcpf(t + 1.f);
}

// ---------- CSR build ----------

__global__ __launch_bounds__(256) void hist_kernel(const int* __restrict__ dst,
                                                   int* __restrict__ counts, int E) {
    int i = blockIdx.x * 256 + threadIdx.x;
    if (i < E) atomicAdd(&counts[dst[i]], 1);
}

__global__ __launch_bounds__(256) void scan1(const int* __restrict__ counts,
                                             int* __restrict__ tmp, int* __restrict__ bsum, int N) {
    __shared__ int wsum[4];
    int b = blockIdx.x, t = threadIdx.x;
    int base = b * 1024 + t * 4;
    int v0 = (base + 0 < N) ? counts[base + 0] : 0;
    int v1 = (base + 1 < N) ? counts[base + 1] : 0;
    int v2 = (base + 2 < N) ? counts[base + 2] : 0;
    int v3 = (base + 3 < N) ? counts[base + 3] : 0;
    int p0 = v0, p1 = p0 + v1, p2 = p1 + v2, p3 = p2 + v3;
    int s = p3;
    int lane = t & 63, wid = t >> 6;
    int sc = s;
    #pragma unroll
    for (int d = 1; d < 64; d <<= 1) {
        int o = __shfl_up(sc, d);
        if (lane >= d) sc += o;
    }
    if (lane == 63) wsum[wid] = sc;
    __syncthreads();
    int wof = 0;
    #pragma unroll
    for (int i = 0; i < 4; ++i) if (i < wid) wof += wsum[i];
    int excl = wof + sc - s;
    if (base + 0 < N) tmp[base + 0] = excl + p0;
    if (base + 1 < N) tmp[base + 1] = excl + p1;
    if (base + 2 < N) tmp[base + 2] = excl + p2;
    if (base + 3 < N) tmp[base + 3] = excl + p3;
    if (t == 255) bsum[b] = wof + sc;
}

__global__ void scan2(int* __restrict__ bsum, int nb) {
    int t = threadIdx.x;
    int v = (t < nb) ? bsum[t] : 0;
    int sc = v;
    #pragma unroll
    for (int d = 1; d < 64; d <<= 1) {
        int o = __shfl_up(sc, d);
        if (t >= d) sc += o;
    }
    if (t < nb) bsum[t] = sc - v;
}

// writes offsets AND cursor (copy_kernel folded in)
__global__ __launch_bounds__(256) void scan3(const int* __restrict__ tmp,
                                             const int* __restrict__ bsum,
                                             int* __restrict__ offsets,
                                             int* __restrict__ cursor, int N) {
    int i = blockIdx.x * 256 + threadIdx.x;
    if (i < N) {
        int v = tmp[i] + bsum[i >> 10];
        offsets[i + 1] = v;
        cursor[i + 1] = v;
    }
    if (i == 0) { offsets[0] = 0; cursor[0] = 0; }
}

__global__ __launch_bounds__(256) void scatter_kernel(const int* __restrict__ dst,
                                                      int* __restrict__ cursor,
                                                      int* __restrict__ eidx, int E) {
    int i = blockIdx.x * 256 + threadIdx.x;
    if (i < E) {
        int p = atomicAdd(&cursor[dst[i]], 1);
        eidx[p] = i;
    }
}

// ---------- 6 weight matrices -> MFMA B-fragments in ONE launch ----------
// blockIdx.x>>3 selects matrix; out stride 2048*8 shorts per matrix.
__global__ __launch_bounds__(256) void make_frag6(
    const float* __restrict__ w0, const float* __restrict__ w1,
    const float* __restrict__ w2, const float* __restrict__ w3,
    const float* __restrict__ w4, const float* __restrict__ w5,
    short* __restrict__ out) {
    int m = blockIdx.x >> 3;
    int id = (blockIdx.x & 7) * 256 + threadIdx.x;   // 0..2047
    const float* W = (m == 0) ? w0 : (m == 1) ? w1 : (m == 2) ? w2
                   : (m == 3) ? w3 : (m == 4) ? w4 : w5;
    int l = id & 63, t16 = id >> 6;
    int kk = t16 & 3, n = t16 >> 2;
    int col = n * 16 + (l & 15);
    int k0 = kk * 32 + (l >> 4) * 8;
    short* o = out + (size_t)m * 2048 * 8 + (size_t)id * 8;
    #pragma unroll
    for (int j = 0; j < 8; ++j)
        o[j] = (short)f2bf(W[col * 128 + k0 + j]);
}

// ---------- qkv GEMM: BARRIER-FREE, no LDS ----------
// Wave w owns rows base+w*16..+15; A-frags loaded straight from global h.
// q,k -> dim-major packed bf16 [node][d16][head]; v standard row-major bf16.

__global__ __launch_bounds__(256) void qkv_gemm(
    const float* __restrict__ X, const short* __restrict__ frag,
    const float* __restrict__ bias,
    u16* __restrict__ Yq, u16* __restrict__ Yk, u16* __restrict__ Yv, int R)
{
    const int t = threadIdx.x;
    const int base = blockIdx.x * 64;
    const int w = t >> 6, l = t & 63, lr = l & 15, lg = l >> 4;

    const int myrow = base + w * 16 + lr;
    const float* xrow = X + (size_t)(myrow < R ? myrow : (R - 1)) * 128;
    bf16x8 afr[4];
    #pragma unroll
    for (int kk = 0; kk < 4; ++kk) {
        float4 f0 = *reinterpret_cast<const float4*>(xrow + kk * 32 + lg * 8);
        float4 f1 = *reinterpret_cast<const float4*>(xrow + kk * 32 + lg * 8 + 4);
        bf16x8 a;
        a[0] = (short)f2bf(f0.x); a[1] = (short)f2bf(f0.y);
        a[2] = (short)f2bf(f0.z); a[3] = (short)f2bf(f0.w);
        a[4] = (short)f2bf(f1.x); a[5] = (short)f2bf(f1.y);
        a[6] = (short)f2bf(f1.z); a[7] = (short)f2bf(f1.w);
        afr[kk] = a;
    }

    for (int ch = 0; ch < 3; ++ch) {
        const bf16x8* bf = reinterpret_cast<const bf16x8*>(frag + (size_t)ch * 2048 * 8);
        f32x4 acc[8];
        #pragma unroll
        for (int n = 0; n < 8; ++n) acc[n] = (f32x4){0.f, 0.f, 0.f, 0.f};
        #pragma unroll
        for (int n = 0; n < 8; ++n)
            #pragma unroll
            for (int kk = 0; kk < 4; ++kk)
                acc[n] = __builtin_amdgcn_mfma_f32_16x16x32_bf16(afr[kk], bf[(n * 4 + kk) * 64 + l],
                                                                 acc[n], 0, 0, 0);
        if (ch < 2) {
            u16* Y = (ch == 0) ? Yq : Yk;
            float bv[8];
            #pragma unroll
            for (int n = 0; n < 8; ++n) bv[n] = bias[ch * 128 + n * 16 + lr];
            #pragma unroll
            for (int reg = 0; reg < 4; ++reg) {
                int r = base + w * 16 + lg * 4 + reg;
                if (r < R) {
                    u16x8 pk;
                    #pragma unroll
                    for (int n = 0; n < 8; ++n) pk[n] = f2bf(acc[n][reg] + bv[n]);
                    *reinterpret_cast<u16x8*>(&Y[(size_t)r * 128 + lr * 8]) = pk;
                }
            }
        } else {
            #pragma unroll
            for (int n = 0; n < 8; ++n) {
                int col = n * 16 + lr;
                float bv = bias[ch * 128 + col];
                #pragma unroll
                for (int reg = 0; reg < 4; ++reg) {
                    int r = base + w * 16 + lg * 4 + reg;
                    if (r < R) Yv[(size_t)r * 128 + col] = f2bf(acc[n][reg] + bv);
                }
            }
        }
    }
}

// ---------- hproj GEMM: BARRIER-FREE, no LDS, f32 out ----------

__global__ __launch_bounds__(256) void gemm128(
    const float* __restrict__ X, const short* __restrict__ frag,
    const float* __restrict__ bias, float* __restrict__ Y, int R)
{
    const int t = threadIdx.x;
    const int base = blockIdx.x * 64;
    const int w = t >> 6, l = t & 63, lr = l & 15, lg = l >> 4;

    const int myrow = base + w * 16 + lr;
    const float* xrow = X + (size_t)(myrow < R ? myrow : (R - 1)) * 128;
    bf16x8 afr[4];
    #pragma unroll
    for (int kk = 0; kk < 4; ++kk) {
        float4 f0 = *reinterpret_cast<const float4*>(xrow + kk * 32 + lg * 8);
        float4 f1 = *reinterpret_cast<const float4*>(xrow + kk * 32 + lg * 8 + 4);
        bf16x8 a;
        a[0] = (short)f2bf(f0.x); a[1] = (short)f2bf(f0.y);
        a[2] = (short)f2bf(f0.z); a[3] = (short)f2bf(f0.w);
        a[4] = (short)f2bf(f1.x); a[5] = (short)f2bf(f1.y);
        a[6] = (short)f2bf(f1.z); a[7] = (short)f2bf(f1.w);
        afr[kk] = a;
    }
    const bf16x8* bf = reinterpret_cast<const bf16x8*>(frag);
    f32x4 acc[8];
    #pragma unroll
    for (int n = 0; n < 8; ++n) acc[n] = (f32x4){0.f, 0.f, 0.f, 0.f};
    #pragma unroll
    for (int n = 0; n < 8; ++n)
        #pragma unroll
        for (int kk = 0; kk < 4; ++kk)
            acc[n] = __builtin_amdgcn_mfma_f32_16x16x32_bf16(afr[kk], bf[(n * 4 + kk) * 64 + l],
                                                             acc[n], 0, 0, 0);
    #pragma unroll
    for (int n = 0; n < 8; ++n) {
        int col = n * 16 + lr;
        float bv = bias[col];
        #pragma unroll
        for (int reg = 0; reg < 4; ++reg) {
            int r = base + w * 16 + lg * 4 + reg;
            if (r < R) Y[(size_t)r * 128 + col] = acc[n][reg] + bv;
        }
    }
}

// ---------- fused edge kernel: BARRIER-FREE (unchanged from R10) ----------

__global__ __launch_bounds__(256) void edge_mfma(
    const float* __restrict__ e, const int* __restrict__ src, const int* __restrict__ dst,
    const short* __restrict__ cfrag, const float* __restrict__ cbias,
    const short* __restrict__ efrag, const float* __restrict__ ebias,
    const u16* __restrict__ qbh, const u16* __restrict__ kbh,
    float* __restrict__ e_out, float* __restrict__ mean_out,
    float* __restrict__ logit, int E)
{
    __shared__ __align__(16) char lds[64 * 256];
    const int t = threadIdx.x;
    const int base = blockIdx.x * 64;
    const int w = t >> 6, l = t & 63;
    const int lr = l & 15, lg = l >> 4;
    const int rowbase = (w * 16 + lr) * 256;
    const int swz = lr << 4;

    int si[4], di[4];
    bool vld[4];
    #pragma unroll
    for (int reg = 0; reg < 4; ++reg) {
        int ei = base + w * 16 + lg * 4 + reg;
        vld[reg] = ei < E;
        int ce = vld[reg] ? ei : (E - 1);
        si[reg] = src[ce];
        di[reg] = dst[ce];
    }
    // gather batch A (heads 0..3): one 8B load per reg per operand
    u16x4 kA[4], qA[4];
    #pragma unroll
    for (int reg = 0; reg < 4; ++reg) {
        kA[reg] = *reinterpret_cast<const u16x4*>(&kbh[(size_t)si[reg] * 128 + lr * 8]);
        qA[reg] = *reinterpret_cast<const u16x4*>(&qbh[(size_t)di[reg] * 128 + lr * 8]);
    }

    // GEMM1 A-fragments straight from global e (own row), f2bf in-register
    const int myrow = base + w * 16 + lr;
    const float* erow = e + (size_t)(myrow < E ? myrow : (E - 1)) * 128;
    bf16x8 afr[4];
    #pragma unroll
    for (int kk = 0; kk < 4; ++kk) {
        float4 f0 = *reinterpret_cast<const float4*>(erow + kk * 32 + lg * 8);
        float4 f1 = *reinterpret_cast<const float4*>(erow + kk * 32 + lg * 8 + 4);
        bf16x8 a;
        a[0] = (short)f2bf(f0.x); a[1] = (short)f2bf(f0.y);
        a[2] = (short)f2bf(f0.z); a[3] = (short)f2bf(f0.w);
        a[4] = (short)f2bf(f1.x); a[5] = (short)f2bf(f1.y);
        a[6] = (short)f2bf(f1.z); a[7] = (short)f2bf(f1.w);
        afr[kk] = a;
    }

    const bf16x8* cf = reinterpret_cast<const bf16x8*>(cfrag);
    float macc[4] = {0.f, 0.f, 0.f, 0.f};

    // ---- half A: GEMM1 n=0..3 + epilogue ----
    {
        f32x4 accA[4];
        #pragma unroll
        for (int n = 0; n < 4; ++n) accA[n] = (f32x4){0.f, 0.f, 0.f, 0.f};
        #pragma unroll
        for (int n = 0; n < 4; ++n)
            #pragma unroll
            for (int kk = 0; kk < 4; ++kk)
                accA[n] = __builtin_amdgcn_mfma_f32_16x16x32_bf16(afr[kk], cf[(n * 4 + kk) * 64 + l],
                                                                  accA[n], 0, 0, 0);
        #pragma unroll
        for (int n = 0; n < 4; ++n) {
            const int col = n * 16 + lr;
            const float cb = cbias[col];
            #pragma unroll
            for (int reg = 0; reg < 4; ++reg) {
                float sc = fast_tanh(accA[n][reg] + cb) * bf2f(kA[reg][n]) * bf2f(qA[reg][n]);
                macc[reg] += sc;
                int row = w * 16 + lg * 4 + reg;
                *reinterpret_cast<u16*>(
                    lds + row * 256 + ((col * 2) ^ ((row & 15) << 4))) = f2bf(sc);
            }
        }
    }

    // gather batch B (heads 4..7)
    u16x4 kB[4], qB[4];
    #pragma unroll
    for (int reg = 0; reg < 4; ++reg) {
        kB[reg] = *reinterpret_cast<const u16x4*>(&kbh[(size_t)si[reg] * 128 + lr * 8 + 4]);
        qB[reg] = *reinterpret_cast<const u16x4*>(&qbh[(size_t)di[reg] * 128 + lr * 8 + 4]);
    }

    // ---- half B: GEMM1 n=4..7 + epilogue ----
    {
        f32x4 accB[4];
        #pragma unroll
        for (int n = 0; n < 4; ++n) accB[n] = (f32x4){0.f, 0.f, 0.f, 0.f};
        #pragma unroll
        for (int n = 0; n < 4; ++n)
            #pragma unroll
            for (int kk = 0; kk < 4; ++kk)
                accB[n] = __builtin_amdgcn_mfma_f32_16x16x32_bf16(afr[kk], cf[((n + 4) * 4 + kk) * 64 + l],
                                                                  accB[n], 0, 0, 0);
        #pragma unroll
        for (int n = 0; n < 4; ++n) {
            const int col = (n + 4) * 16 + lr;
            const float cb = cbias[col];
            #pragma unroll
            for (int reg = 0; reg < 4; ++reg) {
                float sc = fast_tanh(accB[n][reg] + cb) * bf2f(kB[reg][n]) * bf2f(qB[reg][n]);
                macc[reg] += sc;
                int row = w * 16 + lg * 4 + reg;
                *reinterpret_cast<u16*>(
                    lds + row * 256 + ((col * 2) ^ ((row & 15) << 4))) = f2bf(sc);
            }
        }
    }
    #pragma unroll
    for (int reg = 0; reg < 4; ++reg) {
        int ei = base + w * 16 + lg * 4 + reg;
        if (vld[reg]) mean_out[(size_t)ei * 16 + lr] = macc[reg] * 0.125f;
    }

    // A-frags from score (same wave wrote these rows; in-wave ds ordering)
    bf16x8 afr2[4];
    #pragma unroll
    for (int kk = 0; kk < 4; ++kk)
        afr2[kk] = *reinterpret_cast<const bf16x8*>(lds + rowbase + ((kk * 64 + lg * 16) ^ swz));

    // logit via indicator-MFMA: B[k][h] = (k>>4 == h); LINEAR store by edge id
    {
        bf16x8 ind[4];
        #pragma unroll
        for (int kk = 0; kk < 4; ++kk)
            #pragma unroll
            for (int j = 0; j < 8; ++j)
                ind[kk][j] = ((kk * 32 + lg * 8 + j) >> 4 == lr) ? (short)0x3F80 : (short)0;
        f32x4 lac = (f32x4){0.f, 0.f, 0.f, 0.f};
        #pragma unroll
        for (int kk = 0; kk < 4; ++kk)
            lac = __builtin_amdgcn_mfma_f32_16x16x32_bf16(afr2[kk], ind[kk], lac, 0, 0, 0);
        if (lr < 8) {
            #pragma unroll
            for (int reg = 0; reg < 4; ++reg) {
                int ei = base + w * 16 + lg * 4 + reg;
                if (vld[reg]) logit[(size_t)ei * 8 + lr] = lac[reg] * ATTN_SCALE;
            }
        }
    }

    // GEMM2 per-n: e_out = score @ eproj_w.T -> bf16 -> LDS (own rows)
    const bf16x8* ef = reinterpret_cast<const bf16x8*>(efrag);
    #pragma unroll
    for (int n = 0; n < 8; ++n) {
        f32x4 a2 = (f32x4){0.f, 0.f, 0.f, 0.f};
        #pragma unroll
        for (int kk = 0; kk < 4; ++kk)
            a2 = __builtin_amdgcn_mfma_f32_16x16x32_bf16(afr2[kk], ef[(n * 4 + kk) * 64 + l],
                                                         a2, 0, 0, 0);
        const int col = n * 16 + lr;
        const float eb = ebias[col];
        #pragma unroll
        for (int reg = 0; reg < 4; ++reg) {
            int row = w * 16 + lg * 4 + reg;
            *reinterpret_cast<u16*>(
                lds + row * 256 + ((col * 2) ^ ((row & 15) << 4))) = f2bf(a2[reg] + eb);
        }
    }
    // e_out coalesced stores from own rows (wave-private rows)
    #pragma unroll
    for (int rh = 0; rh < 2; ++rh) {
        #pragma unroll
        for (int ih = 0; ih < 2; ++ih) {
            int row = w * 16 + (l >> 3) + 8 * rh;
            int col = (l & 7) * 8 + 64 * ih;
            bf16x8 sv = *reinterpret_cast<const bf16x8*>(
                lds + row * 256 + ((col * 2) ^ ((row & 15) << 4)));
            float4 o0, o1;
            o0.x = bf2f((u16)sv[0]); o0.y = bf2f((u16)sv[1]);
            o0.z = bf2f((u16)sv[2]); o0.w = bf2f((u16)sv[3]);
            o1.x = bf2f((u16)sv[4]); o1.y = bf2f((u16)sv[5]);
            o1.z = bf2f((u16)sv[6]); o1.w = bf2f((u16)sv[7]);
            if (base + row < E) {
                *reinterpret_cast<float4*>(&e_out[(size_t)(base + row) * 128 + col]) = o0;
                *reinterpret_cast<float4*>(&e_out[(size_t)(base + row) * 128 + col + 4]) = o1;
            }
        }
    }
}

// ---------- per-node softmax + aggregation ----------

__global__ __launch_bounds__(256) void node_kernel(
    const int* __restrict__ offsets, const int* __restrict__ eidx,
    const int* __restrict__ src, const float* __restrict__ logit,
    const u16* __restrict__ vbh, float* __restrict__ hagg, int N)
{
    __shared__ int   ls_src[4][64];
    __shared__ float ls_l[4][64][8];
    const int t = threadIdx.x, w = t >> 6, lane = t & 63;
    const int node = blockIdx.x * 4 + w;
    int off = 0, deg = 0;
    if (node < N) { off = offsets[node]; deg = offsets[node + 1] - off; }

    const int h = lane & 7, g = lane >> 3;
    float m = -3.0e38f, s = 0.f;

    for (int c0 = 0; c0 < deg; c0 += 64) {
        int cnt = min(64, deg - c0);
        if (lane < cnt) {
            int eid = eidx[off + c0 + lane];
            ls_src[w][lane] = src[eid];
            float4 l0 = *reinterpret_cast<const float4*>(&logit[(size_t)eid * 8]);
            float4 l1 = *reinterpret_cast<const float4*>(&logit[(size_t)eid * 8 + 4]);
            *reinterpret_cast<float4*>(&ls_l[w][lane][0]) = l0;
            *reinterpret_cast<float4*>(&ls_l[w][lane][4]) = l1;
        }
        __asm__ __volatile__("s_waitcnt lgkmcnt(0)" ::: "memory");
        float cm = -3.0e38f;
        for (int j = g; j < cnt; j += 8) cm = fmaxf(cm, ls_l[w][j][h]);
        cm = fmaxf(cm, __shfl_xor(cm, 8));
        cm = fmaxf(cm, __shfl_xor(cm, 16));
        cm = fmaxf(cm, __shfl_xor(cm, 32));
        float mn = fmaxf(m, cm);
        float cs = 0.f;
        for (int j = g; j < cnt; j += 8) cs += __expf(ls_l[w][j][h] - mn);
        cs += __shfl_xor(cs, 8); cs += __shfl_xor(cs, 16); cs += __shfl_xor(cs, 32);
        s = s * __expf(m - mn) + cs;
        m = mn;
    }
    float inv = (deg > 0) ? 1.f / s : 0.f;

    float a0 = 0.f, a1 = 0.f;
    const int d0 = lane, d1 = lane + 64, h0 = lane >> 4, h1 = 4 + h0;
    for (int c0 = 0; c0 < deg; c0 += 64) {
        int cnt = min(64, deg - c0);
        if (deg > 64 && lane < cnt) {
            int eid = eidx[off + c0 + lane];
            ls_src[w][lane] = src[eid];
            float4 l0 = *reinterpret_cast<const float4*>(&logit[(size_t)eid * 8]);
            float4 l1 = *reinterpret_cast<const float4*>(&logit[(size_t)eid * 8 + 4]);
            *reinterpret_cast<float4*>(&ls_l[w][lane][0]) = l0;
            *reinterpret_cast<float4*>(&ls_l[w][lane][4]) = l1;
        }
        __asm__ __volatile__("s_waitcnt lgkmcnt(0)" ::: "memory");
        for (int j = g; j < cnt; j += 8)
            ls_l[w][j][h] = __expf(ls_l[w][j][h] - m) * inv;
        __asm__ __volatile__("s_waitcnt lgkmcnt(0)" ::: "memory");
        #pragma unroll 4
        for (int j = 0; j < cnt; ++j) {
            int sn = ls_src[w][j];
            float w0 = ls_l[w][j][h0], w1 = ls_l[w][j][h1];
            a0 += w0 * bf2f(vbh[(size_t)sn * 128 + d0]);
            a1 += w1 * bf2f(vbh[(size_t)sn * 128 + d1]);
        }
    }
    if (node < N) {
        hagg[(size_t)node * 128 + d0] = a0;
        hagg[(size_t)node * 128 + d1] = a1;
    }
}

// ---------- launcher ----------

extern "C" void kernel_launch(void* const* d_in, const int* in_sizes, int n_in,
                              void* d_out, int out_size, void* d_ws, size_t ws_size,
                              hipStream_t stream)
{
    const float* h       = (const float*)d_in[0];
    const float* e       = (const float*)d_in[1];
    const int*   src     = (const int*)d_in[2];
    const int*   dst     = (const int*)d_in[3];
    const float* qkv_w   = (const float*)d_in[4];
    const float* qkv_b   = (const float*)d_in[5];
    const float* c_w     = (const float*)d_in[6];
    const float* c_b     = (const float*)d_in[7];
    const float* hproj_w = (const float*)d_in[8];
    const float* hproj_b = (const float*)d_in[9];
    const float* eproj_w = (const float*)d_in[10];
    const float* eproj_b = (const float*)d_in[11];

    const int N = in_sizes[0] / 128;
    const int E = in_sizes[1] / 128;

    float* h_out    = (float*)d_out;
    float* e_out    = h_out + (size_t)N * 128;
    float* mean_out = e_out + (size_t)E * 128;

    char* wp = (char*)d_ws;
    auto alloc = [&](size_t b) {
        void* p = (void*)wp;
        wp += (b + 255) & ~(size_t)255;
        return p;
    };
    // fragments: [qkv0, qkv1, qkv2, c, eproj, hproj] in one buffer
    short* fragbuf = (short*)alloc(sizeof(short) * 6 * 2048 * 8);
    u16*   qbh     = (u16*)alloc(sizeof(u16) * (size_t)N * 128);
    u16*   kbh     = (u16*)alloc(sizeof(u16) * (size_t)N * 128);
    u16*   vbh     = (u16*)alloc(sizeof(u16) * (size_t)N * 128);
    float* hagg    = (float*)alloc(sizeof(float) * (size_t)N * 128);
    float* logit   = (float*)alloc(sizeof(float) * (size_t)E * 8);
    int*   counts  = (int*)alloc(sizeof(int) * (N + 1));
    int*   offs    = (int*)alloc(sizeof(int) * (N + 1));
    int*   cursor  = (int*)alloc(sizeof(int) * (N + 1));
    int*   stmp    = (int*)alloc(sizeof(int) * (N + 1));
    int*   bsum    = (int*)alloc(sizeof(int) * 64);
    int*   eidx    = (int*)alloc(sizeof(int) * E);

    short* qkvfrag = fragbuf;
    short* cfragb  = fragbuf + (size_t)3 * 2048 * 8;
    short* efragb  = fragbuf + (size_t)4 * 2048 * 8;
    short* hpfrag  = fragbuf + (size_t)5 * 2048 * 8;

    hipMemsetAsync(counts, 0, sizeof(int) * (N + 1), stream);

    make_frag6<<<48, 256, 0, stream>>>(qkv_w, qkv_w + 128 * 128, qkv_w + 2 * 128 * 128,
                                       c_w, eproj_w, hproj_w, fragbuf);

    qkv_gemm<<<(N + 63) / 64, 256, 0, stream>>>(h, qkvfrag, qkv_b, qbh, kbh, vbh, N);

    hist_kernel<<<(E + 255) / 256, 256, 0, stream>>>(dst, counts, E);
    int nb = (N + 1023) / 1024;
    scan1<<<nb, 256, 0, stream>>>(counts, stmp, bsum, N);
    scan2<<<1, 64, 0, stream>>>(bsum, nb);
    scan3<<<(N + 255) / 256, 256, 0, stream>>>(stmp, bsum, offs, cursor, N);
    scatter_kernel<<<(E + 255) / 256, 256, 0, stream>>>(dst, cursor, eidx, E);

    edge_mfma<<<(E + 63) / 64, 256, 0, stream>>>(e, src, dst, cfragb, c_b, efragb,
                                                 eproj_b, qbh, kbh, e_out, mean_out, logit, E);

    node_kernel<<<(N + 3) / 4, 256, 0, stream>>>(offs, eidx, src, logit, vbh, hagg, N);

    gemm128<<<(N + 63) / 64, 256, 0, stream>>>(hagg, hpfrag, hproj_b, h_out, N);
}